// Round 1
// baseline (1442.266 us; speedup 1.0000x reference)
//
#include <hip/hip_runtime.h>
#include <math.h>

#define NCAM  6
#define INC   256
#define HH    56
#define WW    100
#define HW    5600
#define NPIX  33600
#define DDEP  41
#define CFEAT 64
#define NCH   105          // 41 depth + 64 feat
#define NXG   33
#define NYG   33
#define NZG   2
#define NVOX  2178         // 2*33*33
#define PADW  35
#define PADHW 1225         // 35*35
#define NPIXO 1089         // 33*33

// ---- workspace layout (floats) ----
#define Y_OFF   0
#define Y_SZ    (NCAM * NCH * HW)          // 3,528,000
#define BEV_OFF (Y_OFF + Y_SZ)
#define BEV_SZ  (NVOX * CFEAT)             // 139,392
#define B0_OFF  (BEV_OFF + BEV_SZ)
#define B0_SZ   (128 * PADHW)
#define B1_OFF  (B0_OFF + B0_SZ)
#define B1_SZ   (128 * PADHW)
#define B2_OFF  (B1_OFF + B1_SZ)
#define B2_SZ   (512 * PADHW)
#define B3_OFF  (B2_OFF + B2_SZ)
#define B3_SZ   (512 * PADHW)
#define WS_END  (B3_OFF + B3_SZ)           // 5,235,392 floats ~ 21 MB

__device__ __forceinline__ void fma4(float4& a, float w, const float4& x) {
    a.x = fmaf(w, x.x, a.x);
    a.y = fmaf(w, x.y, a.y);
    a.z = fmaf(w, x.z, a.z);
    a.w = fmaf(w, x.w, a.w);
}

// ---------------- Stage 1: depthnet 1x1 conv (GEMM 33600 x 105 x 256) -------
// block: 256 thr = 16 pxg (4 px each, 64 px/block) x 16 cg (c = cc*16+cg)
__global__ __launch_bounds__(256) void k_depthnet(const float* __restrict__ x,
                                                  const float* __restrict__ dnw,
                                                  const float* __restrict__ dnb,
                                                  float* __restrict__ y)
{
    __shared__ float xs[64 * 64];     // [ci][px]
    __shared__ float wsh[105 * 68];   // [c][ci], row stride 68 (conflict-free)
    const int t   = threadIdx.x;
    const int pxg = t & 15;
    const int cg  = t >> 4;
    const int n   = blockIdx.y;
    const int hw0 = blockIdx.x * 64;
    const int nrem = HW - hw0;        // >= 32
    const float* xn = x + (size_t)n * INC * HW;

    float4 acc[7];
#pragma unroll
    for (int i = 0; i < 7; ++i) acc[i] = make_float4(0.f, 0.f, 0.f, 0.f);

    for (int ci0 = 0; ci0 < INC; ci0 += 64) {
        __syncthreads();
        for (int i = t; i < 4096; i += 256) {
            int ci = i >> 6, px = i & 63;
            xs[i] = (px < nrem) ? xn[(size_t)(ci0 + ci) * HW + hw0 + px] : 0.f;
        }
        for (int i = t; i < 6720; i += 256) {
            int c = i >> 6, ci = i & 63;
            wsh[c * 68 + ci] = dnw[c * 256 + ci0 + ci];
        }
        __syncthreads();
#pragma unroll 4
        for (int ci = 0; ci < 64; ci += 4) {
            float4 xv0 = *(const float4*)&xs[(ci + 0) * 64 + pxg * 4];
            float4 xv1 = *(const float4*)&xs[(ci + 1) * 64 + pxg * 4];
            float4 xv2 = *(const float4*)&xs[(ci + 2) * 64 + pxg * 4];
            float4 xv3 = *(const float4*)&xs[(ci + 3) * 64 + pxg * 4];
#pragma unroll
            for (int cc = 0; cc < 7; ++cc) {
                int c = cc * 16 + cg;
                if (c < NCH) {
                    float4 wq = *(const float4*)&wsh[c * 68 + ci];
                    fma4(acc[cc], wq.x, xv0);
                    fma4(acc[cc], wq.y, xv1);
                    fma4(acc[cc], wq.z, xv2);
                    fma4(acc[cc], wq.w, xv3);
                }
            }
        }
    }
    const int px = pxg * 4;
    if (px < nrem) {
#pragma unroll
        for (int cc = 0; cc < 7; ++cc) {
            int c = cc * 16 + cg;
            if (c < NCH) {
                float b = dnb[c];
                float4 o = acc[cc];
                o.x += b; o.y += b; o.z += b; o.w += b;
                *(float4*)&y[((size_t)n * NCH + c) * HW + hw0 + px] = o;
            }
        }
    }
}

// ---------------- Stage 2: softmax over 41 depth channels (in place) -------
__global__ __launch_bounds__(256) void k_softmax(float* __restrict__ y)
{
    int p = blockIdx.x * 256 + threadIdx.x;
    if (p >= NPIX) return;
    int n = p / HW, hw = p - n * HW;
    float* base = y + (size_t)n * NCH * HW + hw;
    float v[DDEP];
    float m = -3.4e38f;
#pragma unroll
    for (int d = 0; d < DDEP; ++d) { v[d] = base[(size_t)d * HW]; m = fmaxf(m, v[d]); }
    float s = 0.f;
#pragma unroll
    for (int d = 0; d < DDEP; ++d) { v[d] = expf(v[d] - m); s += v[d]; }
#pragma unroll
    for (int d = 0; d < DDEP; ++d) base[(size_t)d * HW] = v[d] / s;
}

// ---------------- Stage 3: geometry + lift + splat (atomics) ---------------
// Geometry arithmetic uses rn-intrinsics to suppress FMA contraction so the
// truncation-to-voxel boundaries match the numpy reference's mul/add ordering.
__global__ __launch_bounds__(256) void k_splat(const float* __restrict__ y,
                                               const float* __restrict__ rots,
                                               const float* __restrict__ trans,
                                               float* __restrict__ bev)
{
    int p = blockIdx.x * 256 + threadIdx.x;
    if (p >= NPIX) return;
    int n = p / HW, hw = p - n * HW;
    int wi = hw % WW, hi = hw / WW;
    const float su = 1599.0f / 99.0f;   // jnp.linspace(0,1599,100) step, fp32
    const float sv = 899.0f / 55.0f;    // jnp.linspace(0,899,56) step, fp32
    float u = __fmul_rn((float)wi, su);
    float v = __fmul_rn((float)hi, sv);
    const float* r = rots + n * 9;
    float r00 = r[0], r01 = r[1], r02 = r[2];
    float r10 = r[3], r11 = r[4], r12 = r[5];
    float r20 = r[6], r21 = r[7], r22 = r[8];
    const float* tr = trans + n * 3;
    float t0 = tr[0], t1 = tr[1], t2 = tr[2];
    const float* dbase = y + (size_t)n * NCH * HW + hw;
    const float* fbase = dbase + (size_t)DDEP * HW;

    for (int di = 0; di < DDEP; ++di) {
        float dd  = 4.0f + (float)di;
        float pxv = __fmul_rn(u, dd);
        float pyv = __fmul_rn(v, dd);
        float gx = __fadd_rn(__fadd_rn(__fadd_rn(__fmul_rn(r00, pxv), __fmul_rn(r01, pyv)), __fmul_rn(r02, dd)), t0);
        float gy = __fadd_rn(__fadd_rn(__fadd_rn(__fmul_rn(r10, pxv), __fmul_rn(r11, pyv)), __fmul_rn(r12, dd)), t1);
        float gz = __fadd_rn(__fadd_rn(__fadd_rn(__fmul_rn(r20, pxv), __fmul_rn(r21, pyv)), __fmul_rn(r22, dd)), t2);
        // (geom - (bx - dx/2)) / dx with bx-dx/2 = {-50,-50,-5}; trunc toward 0
        int cx = (int)__fdiv_rn(__fadd_rn(gx, 50.0f), 3.0f);
        int cy = (int)__fdiv_rn(__fadd_rn(gy, 50.0f), 3.0f);
        int cz = (int)__fdiv_rn(__fadd_rn(gz, 5.0f), 3.0f);
        if (cx >= 0 && cx < NXG && cy >= 0 && cy < NYG && cz >= 0 && cz < NZG) {
            float dval = dbase[(size_t)di * HW];
            float* vp = bev + (size_t)((cz * NYG + cy) * NXG + cx) * CFEAT;
#pragma unroll 8
            for (int c = 0; c < CFEAT; ++c) {
                atomicAdd(vp + c, __fmul_rn(dval, fbase[(size_t)c * HW]));
            }
        }
    }
}

// ---------------- Stage 4: bev [vox][c] -> padded NCHW [c*2+cz][35][35] ----
__global__ __launch_bounds__(256) void k_bev2chw(const float* __restrict__ bev,
                                                 float* __restrict__ b0)
{
    int i = blockIdx.x * 256 + threadIdx.x;
    if (i >= NVOX * CFEAT) return;
    int vx = i >> 6, c = i & 63;
    int cz = vx / NPIXO, rem = vx - cz * NPIXO;
    int yy = rem / NXG, xx = rem - yy * NXG;
    b0[(size_t)(c * 2 + cz) * PADHW + (yy + 1) * PADW + (xx + 1)] = bev[i];
}

// ---------------- Stage 5: 3x3 conv + BN(eval) + ReLU ----------------------
// block: 256 thr = 8 cg (4 co each -> 32 co/block) x 32 pxg (4 px -> 128 px)
// grid: (9 px tiles, COUT/32)
template<int CIN>
__global__ __launch_bounds__(256) void k_conv3x3(const float* __restrict__ in,   // [CIN][35][35]
                                                 const float* __restrict__ wgt,  // [COUT][CIN][3][3]
                                                 const float* __restrict__ bns,
                                                 const float* __restrict__ bnb,
                                                 const float* __restrict__ bnm,
                                                 const float* __restrict__ bnv,
                                                 float* __restrict__ out,
                                                 int out_padded)
{
    __shared__ float ws[144 * 36];   // [ci*9+k][co], row stride 36 (16B-aligned, conflict-free)
    __shared__ float xs[16 * 245];   // [ci][7 rows * 35]
    const int t   = threadIdx.x;
    const int cg  = t >> 5;          // 0..7
    const int pxg = t & 31;          // 0..31
    const int cob = blockIdx.y * 32;
    const int px0 = blockIdx.x * 128;
    const int y_first = px0 / 33;

    const int pbase = px0 + pxg * 4;
    int  base[4];
    bool val[4];
#pragma unroll
    for (int j = 0; j < 4; ++j) {
        int p = pbase + j;
        val[j] = (p < NPIXO);
        if (val[j]) {
            int yv = p / 33, xv = p - yv * 33;
            base[j] = (yv - y_first) * 35 + xv;
        } else {
            base[j] = 0;
        }
    }

    float acc[4][4];
#pragma unroll
    for (int j = 0; j < 4; ++j)
#pragma unroll
        for (int i = 0; i < 4; ++i) acc[j][i] = 0.f;

    for (int ci0 = 0; ci0 < CIN; ci0 += 16) {
        __syncthreads();
        for (int i = t; i < 4608; i += 256) {             // weights, coalesced reads
            int co = i / 144, rem = i - co * 144;         // rem = ci_l*9 + k
            ws[rem * 36 + co] = wgt[(size_t)(cob + co) * CIN * 9 + (size_t)ci0 * 9 + rem];
        }
        for (int i = t; i < 3920; i += 256) {             // input tile (7 padded rows)
            int ci = i / 245, rem = i - ci * 245;
            int row = y_first + rem / 35;
            int col = rem % 35;
            xs[i] = (row < PADW) ? in[(size_t)(ci0 + ci) * PADHW + row * PADW + col] : 0.f;
        }
        __syncthreads();
#pragma unroll 4
        for (int ci = 0; ci < 16; ++ci) {
#pragma unroll
            for (int dy = 0; dy < 3; ++dy) {
#pragma unroll
                for (int dx = 0; dx < 3; ++dx) {
                    float4 wv = *(const float4*)&ws[(ci * 9 + dy * 3 + dx) * 36 + cg * 4];
#pragma unroll
                    for (int j = 0; j < 4; ++j) {
                        float xv = xs[ci * 245 + base[j] + dy * 35 + dx];
                        acc[j][0] = fmaf(wv.x, xv, acc[j][0]);
                        acc[j][1] = fmaf(wv.y, xv, acc[j][1]);
                        acc[j][2] = fmaf(wv.z, xv, acc[j][2]);
                        acc[j][3] = fmaf(wv.w, xv, acc[j][3]);
                    }
                }
            }
        }
    }

#pragma unroll
    for (int i = 0; i < 4; ++i) {
        int co = cob + cg * 4 + i;
        float sc = bns[co] / sqrtf(bnv[co] + 1e-5f);
        float bi = bnb[co] - bnm[co] * sc;
#pragma unroll
        for (int j = 0; j < 4; ++j) {
            if (val[j]) {
                float rv = fmaxf(fmaf(acc[j][i], sc, bi), 0.f);
                int p = pbase + j;
                if (out_padded) {
                    int yv = p / 33, xv = p - yv * 33;
                    out[(size_t)co * PADHW + (yv + 1) * PADW + (xv + 1)] = rv;
                } else {
                    out[(size_t)co * NPIXO + p] = rv;
                }
            }
        }
    }
}

extern "C" void kernel_launch(void* const* d_in, const int* in_sizes, int n_in,
                              void* d_out, int out_size, void* d_ws, size_t ws_size,
                              hipStream_t stream)
{
    const float* x     = (const float*)d_in[0];
    const float* rots  = (const float*)d_in[1];
    const float* trans = (const float*)d_in[2];
    const float* dnw   = (const float*)d_in[3];
    const float* dnb   = (const float*)d_in[4];
    const float* bw1   = (const float*)d_in[5];
    const float* bn1s  = (const float*)d_in[6];
    const float* bn1b  = (const float*)d_in[7];
    const float* bn1m  = (const float*)d_in[8];
    const float* bn1v  = (const float*)d_in[9];
    const float* bw2   = (const float*)d_in[10];
    const float* bn2s  = (const float*)d_in[11];
    const float* bn2b  = (const float*)d_in[12];
    const float* bn2m  = (const float*)d_in[13];
    const float* bn2v  = (const float*)d_in[14];
    const float* bw3   = (const float*)d_in[15];
    const float* bn3s  = (const float*)d_in[16];
    const float* bn3b  = (const float*)d_in[17];
    const float* bn3m  = (const float*)d_in[18];
    const float* bn3v  = (const float*)d_in[19];
    const float* bw4   = (const float*)d_in[20];
    const float* bn4s  = (const float*)d_in[21];
    const float* bn4b  = (const float*)d_in[22];
    const float* bn4m  = (const float*)d_in[23];
    const float* bn4v  = (const float*)d_in[24];

    float* ws  = (float*)d_ws;
    float* y   = ws + Y_OFF;
    float* bev = ws + BEV_OFF;
    float* b0  = ws + B0_OFF;
    float* b1  = ws + B1_OFF;
    float* b2  = ws + B2_OFF;
    float* b3  = ws + B3_OFF;
    float* out = (float*)d_out;

    // zero the atomic accumulator + padded conv buffers (borders) every call
    hipMemsetAsync(bev, 0, (size_t)(WS_END - BEV_OFF) * sizeof(float), stream);

    k_depthnet<<<dim3(88, 6), 256, 0, stream>>>(x, dnw, dnb, y);
    k_softmax<<<132, 256, 0, stream>>>(y);
    k_splat<<<132, 256, 0, stream>>>(y, rots, trans, bev);
    k_bev2chw<<<545, 256, 0, stream>>>(bev, b0);
    k_conv3x3<128><<<dim3(9, 4),  256, 0, stream>>>(b0, bw1, bn1s, bn1b, bn1m, bn1v, b1, 1);
    k_conv3x3<128><<<dim3(9, 16), 256, 0, stream>>>(b1, bw2, bn2s, bn2b, bn2m, bn2v, b2, 1);
    k_conv3x3<512><<<dim3(9, 16), 256, 0, stream>>>(b2, bw3, bn3s, bn3b, bn3m, bn3v, b3, 1);
    k_conv3x3<512><<<dim3(9, 8),  256, 0, stream>>>(b3, bw4, bn4s, bn4b, bn4m, bn4v, out, 0);
}

// Round 2
// 452.485 us; speedup vs baseline: 3.1874x; 3.1874x over previous
//
#include <hip/hip_runtime.h>
#include <math.h>

#define NCAM  6
#define INC   256
#define HH    56
#define WW    100
#define HW    5600
#define NPIX  33600
#define DDEP  41
#define CFEAT 64
#define NCH   105          // 41 depth + 64 feat
#define NXG   33
#define NYG   33
#define NZG   2
#define NVOX  2178         // 2*33*33
#define PADW  35
#define PADHW 1225         // 35*35
#define NPIXO 1089         // 33*33

// ---- workspace layout (floats) ----
#define Y_OFF   0
#define Y_SZ    (NCAM * NCH * HW)          // 3,528,000 (also reused as conv partial buffer)
#define BEV_OFF (Y_OFF + Y_SZ)
#define BEV_SZ  (NVOX * CFEAT)             // 139,392
#define B0_OFF  (BEV_OFF + BEV_SZ)
#define B0_SZ   (128 * PADHW)
#define B1_OFF  (B0_OFF + B0_SZ)
#define B1_SZ   (128 * PADHW)
#define B2_OFF  (B1_OFF + B1_SZ)
#define B2_SZ   (512 * PADHW)
#define B3_OFF  (B2_OFF + B2_SZ)
#define B3_SZ   (512 * PADHW)
#define WS_END  (B3_OFF + B3_SZ)

__device__ __forceinline__ void fma4(float4& a, float w, const float4& x) {
    a.x = fmaf(w, x.x, a.x);
    a.y = fmaf(w, x.y, a.y);
    a.z = fmaf(w, x.z, a.z);
    a.w = fmaf(w, x.w, a.w);
}

// ---------------- Stage 1: depthnet 1x1 conv (GEMM 33600 x 105 x 256) -------
__global__ __launch_bounds__(256) void k_depthnet(const float* __restrict__ x,
                                                  const float* __restrict__ dnw,
                                                  const float* __restrict__ dnb,
                                                  float* __restrict__ y)
{
    __shared__ float xs[64 * 64];     // [ci][px]
    __shared__ float wsh[105 * 68];   // [c][ci]
    const int t   = threadIdx.x;
    const int pxg = t & 15;
    const int cg  = t >> 4;
    const int n   = blockIdx.y;
    const int hw0 = blockIdx.x * 64;
    const int nrem = HW - hw0;
    const float* xn = x + (size_t)n * INC * HW;

    float4 acc[7];
#pragma unroll
    for (int i = 0; i < 7; ++i) acc[i] = make_float4(0.f, 0.f, 0.f, 0.f);

    for (int ci0 = 0; ci0 < INC; ci0 += 64) {
        __syncthreads();
        for (int i = t; i < 4096; i += 256) {
            int ci = i >> 6, px = i & 63;
            xs[i] = (px < nrem) ? xn[(size_t)(ci0 + ci) * HW + hw0 + px] : 0.f;
        }
        for (int i = t; i < 6720; i += 256) {
            int c = i >> 6, ci = i & 63;
            wsh[c * 68 + ci] = dnw[c * 256 + ci0 + ci];
        }
        __syncthreads();
#pragma unroll 4
        for (int ci = 0; ci < 64; ci += 4) {
            float4 xv0 = *(const float4*)&xs[(ci + 0) * 64 + pxg * 4];
            float4 xv1 = *(const float4*)&xs[(ci + 1) * 64 + pxg * 4];
            float4 xv2 = *(const float4*)&xs[(ci + 2) * 64 + pxg * 4];
            float4 xv3 = *(const float4*)&xs[(ci + 3) * 64 + pxg * 4];
#pragma unroll
            for (int cc = 0; cc < 7; ++cc) {
                int c = cc * 16 + cg;
                if (c < NCH) {
                    float4 wq = *(const float4*)&wsh[c * 68 + ci];
                    fma4(acc[cc], wq.x, xv0);
                    fma4(acc[cc], wq.y, xv1);
                    fma4(acc[cc], wq.z, xv2);
                    fma4(acc[cc], wq.w, xv3);
                }
            }
        }
    }
    const int px = pxg * 4;
    if (px < nrem) {
#pragma unroll
        for (int cc = 0; cc < 7; ++cc) {
            int c = cc * 16 + cg;
            if (c < NCH) {
                float b = dnb[c];
                float4 o = acc[cc];
                o.x += b; o.y += b; o.z += b; o.w += b;
                *(float4*)&y[((size_t)n * NCH + c) * HW + hw0 + px] = o;
            }
        }
    }
}

// ---------------- Stage 2: softmax over 41 depth channels (in place) -------
__global__ __launch_bounds__(256) void k_softmax(float* __restrict__ y)
{
    int p = blockIdx.x * 256 + threadIdx.x;
    if (p >= NPIX) return;
    int n = p / HW, hw = p - n * HW;
    float* base = y + (size_t)n * NCH * HW + hw;
    float v[DDEP];
    float m = -3.4e38f;
#pragma unroll
    for (int d = 0; d < DDEP; ++d) { v[d] = base[(size_t)d * HW]; m = fmaxf(m, v[d]); }
    float s = 0.f;
#pragma unroll
    for (int d = 0; d < DDEP; ++d) { v[d] = expf(v[d] - m); s += v[d]; }
#pragma unroll
    for (int d = 0; d < DDEP; ++d) base[(size_t)d * HW] = v[d] / s;
}

// ---------------- Stage 3: geometry + lift + splat (atomics) ---------------
// One thread per (depth, pixel); rn-intrinsics keep voxel-truncation
// boundaries bit-identical to the numpy reference's mul/add ordering.
__global__ __launch_bounds__(256) void k_splat(const float* __restrict__ y,
                                               const float* __restrict__ rots,
                                               const float* __restrict__ trans,
                                               float* __restrict__ bev)
{
    int idx = blockIdx.x * 256 + threadIdx.x;
    if (idx >= NPIX * DDEP) return;
    int di = idx / NPIX;
    int p  = idx - di * NPIX;
    int n = p / HW, hw = p - n * HW;
    int wi = hw % WW, hi = hw / WW;
    const float su = 1599.0f / 99.0f;
    const float sv = 899.0f / 55.0f;
    float u = __fmul_rn((float)wi, su);
    float v = __fmul_rn((float)hi, sv);
    const float* r = rots + n * 9;
    const float* tr = trans + n * 3;
    float dd  = 4.0f + (float)di;
    float pxv = __fmul_rn(u, dd);
    float pyv = __fmul_rn(v, dd);
    float gx = __fadd_rn(__fadd_rn(__fadd_rn(__fmul_rn(r[0], pxv), __fmul_rn(r[1], pyv)), __fmul_rn(r[2], dd)), tr[0]);
    float gy = __fadd_rn(__fadd_rn(__fadd_rn(__fmul_rn(r[3], pxv), __fmul_rn(r[4], pyv)), __fmul_rn(r[5], dd)), tr[1]);
    float gz = __fadd_rn(__fadd_rn(__fadd_rn(__fmul_rn(r[6], pxv), __fmul_rn(r[7], pyv)), __fmul_rn(r[8], dd)), tr[2]);
    int cx = (int)__fdiv_rn(__fadd_rn(gx, 50.0f), 3.0f);
    int cy = (int)__fdiv_rn(__fadd_rn(gy, 50.0f), 3.0f);
    int cz = (int)__fdiv_rn(__fadd_rn(gz, 5.0f), 3.0f);
    if (cx >= 0 && cx < NXG && cy >= 0 && cy < NYG && cz >= 0 && cz < NZG) {
        const float* dbase = y + (size_t)n * NCH * HW + hw;
        const float* fbase = dbase + (size_t)DDEP * HW;
        float dval = dbase[(size_t)di * HW];
        float* vp = bev + (size_t)((cz * NYG + cy) * NXG + cx) * CFEAT;
#pragma unroll 8
        for (int c = 0; c < CFEAT; ++c) {
            atomicAdd(vp + c, __fmul_rn(dval, fbase[(size_t)c * HW]));
        }
    }
}

// ---------------- Stage 4: bev [vox][c] -> padded NCHW [c*2+cz][35][35] ----
__global__ __launch_bounds__(256) void k_bev2chw(const float* __restrict__ bev,
                                                 float* __restrict__ b0)
{
    int i = blockIdx.x * 256 + threadIdx.x;
    if (i >= NVOX * CFEAT) return;
    int vx = i >> 6, c = i & 63;
    int cz = vx / NPIXO, rem = vx - cz * NPIXO;
    int yy = rem / NXG, xx = rem - yy * NXG;
    b0[(size_t)(c * 2 + cz) * PADHW + (yy + 1) * PADW + (xx + 1)] = bev[i];
}

// ---------------- Stage 5a: 3x3 conv partial sums (CI-split) ---------------
// block: 256 thr = 8 cg (4 co each -> 32 co/block) x 32 pxg (4 px stride-32)
// grid: (9 px tiles, COUT/32, SLICES).  Writes P[slice][co][px] (flat 1089).
template<int CIN, int SLICES>
__global__ __launch_bounds__(256) void k_conv_part(const float* __restrict__ in,   // [CIN][35][35]
                                                   const float* __restrict__ wgt,  // [COUT][CIN][3][3]
                                                   float* __restrict__ P,
                                                   int COUT)
{
    constexpr int CI_PER = CIN / SLICES;
    __shared__ float ws[144 * 36];   // [ci_l*9+k][co], stride 36 (16B aligned)
    __shared__ float xs[16 * 245];   // [ci][7 rows * 35]
    const int t   = threadIdx.x;
    const int cg  = t >> 5;          // 0..7
    const int pxg = t & 31;          // 0..31
    const int cob = blockIdx.y * 32;
    const int px0 = blockIdx.x * 128;
    const int sl  = blockIdx.z;
    const int y_first = px0 / 33;

    int  base[4];
    bool val[4];
#pragma unroll
    for (int j = 0; j < 4; ++j) {
        int p = px0 + pxg + j * 32;
        val[j] = (p < NPIXO);
        if (val[j]) {
            int yv = p / 33, xv = p - yv * 33;
            base[j] = (yv - y_first) * 35 + xv;
        } else {
            base[j] = 0;
        }
    }

    float acc[4][4];
#pragma unroll
    for (int j = 0; j < 4; ++j)
#pragma unroll
        for (int i = 0; i < 4; ++i) acc[j][i] = 0.f;

    for (int c16 = 0; c16 < CI_PER; c16 += 16) {
        const int ci0 = sl * CI_PER + c16;
        __syncthreads();
        for (int i = t; i < 4608; i += 256) {             // weights
            int co = i / 144, rem = i - co * 144;
            ws[rem * 36 + co] = wgt[(size_t)(cob + co) * CIN * 9 + (size_t)ci0 * 9 + rem];
        }
        for (int i = t; i < 3920; i += 256) {             // input tile (7 rows)
            int ci = i / 245, rem = i - ci * 245;
            int row = y_first + rem / 35;
            int col = rem % 35;
            xs[i] = (row < PADW) ? in[(size_t)(ci0 + ci) * PADHW + row * PADW + col] : 0.f;
        }
        __syncthreads();
#pragma unroll 4
        for (int ci = 0; ci < 16; ++ci) {
#pragma unroll
            for (int dy = 0; dy < 3; ++dy) {
#pragma unroll
                for (int dx = 0; dx < 3; ++dx) {
                    float4 wv = *(const float4*)&ws[(ci * 9 + dy * 3 + dx) * 36 + cg * 4];
#pragma unroll
                    for (int j = 0; j < 4; ++j) {
                        float xv = xs[ci * 245 + base[j] + dy * 35 + dx];
                        acc[j][0] = fmaf(wv.x, xv, acc[j][0]);
                        acc[j][1] = fmaf(wv.y, xv, acc[j][1]);
                        acc[j][2] = fmaf(wv.z, xv, acc[j][2]);
                        acc[j][3] = fmaf(wv.w, xv, acc[j][3]);
                    }
                }
            }
        }
    }

#pragma unroll
    for (int i = 0; i < 4; ++i) {
        int co = cob + cg * 4 + i;
        float* Pc = P + ((size_t)sl * COUT + co) * NPIXO;
#pragma unroll
        for (int j = 0; j < 4; ++j) {
            if (val[j]) Pc[px0 + pxg + j * 32] = acc[j][i];
        }
    }
}

// ---------------- Stage 5b: reduce slices + BN(eval) + ReLU ----------------
template<int SLICES>
__global__ __launch_bounds__(256) void k_conv_finish(const float* __restrict__ P,
                                                     const float* __restrict__ bns,
                                                     const float* __restrict__ bnb,
                                                     const float* __restrict__ bnm,
                                                     const float* __restrict__ bnv,
                                                     float* __restrict__ out,
                                                     int COUT, int out_padded)
{
    int i = blockIdx.x * 256 + threadIdx.x;
    if (i >= COUT * NPIXO) return;
    int co = i / NPIXO, p = i - co * NPIXO;
    float s = 0.f;
#pragma unroll
    for (int sl = 0; sl < SLICES; ++sl)
        s += P[((size_t)sl * COUT + co) * NPIXO + p];
    float sc = bns[co] / sqrtf(bnv[co] + 1e-5f);
    float bi = bnb[co] - bnm[co] * sc;
    float rv = fmaxf(fmaf(s, sc, bi), 0.f);
    if (out_padded) {
        int yv = p / 33, xv = p - yv * 33;
        out[(size_t)co * PADHW + (yv + 1) * PADW + (xv + 1)] = rv;
    } else {
        out[(size_t)co * NPIXO + p] = rv;
    }
}

extern "C" void kernel_launch(void* const* d_in, const int* in_sizes, int n_in,
                              void* d_out, int out_size, void* d_ws, size_t ws_size,
                              hipStream_t stream)
{
    const float* x     = (const float*)d_in[0];
    const float* rots  = (const float*)d_in[1];
    const float* trans = (const float*)d_in[2];
    const float* dnw   = (const float*)d_in[3];
    const float* dnb   = (const float*)d_in[4];
    const float* bw1   = (const float*)d_in[5];
    const float* bn1s  = (const float*)d_in[6];
    const float* bn1b  = (const float*)d_in[7];
    const float* bn1m  = (const float*)d_in[8];
    const float* bn1v  = (const float*)d_in[9];
    const float* bw2   = (const float*)d_in[10];
    const float* bn2s  = (const float*)d_in[11];
    const float* bn2b  = (const float*)d_in[12];
    const float* bn2m  = (const float*)d_in[13];
    const float* bn2v  = (const float*)d_in[14];
    const float* bw3   = (const float*)d_in[15];
    const float* bn3s  = (const float*)d_in[16];
    const float* bn3b  = (const float*)d_in[17];
    const float* bn3m  = (const float*)d_in[18];
    const float* bn3v  = (const float*)d_in[19];
    const float* bw4   = (const float*)d_in[20];
    const float* bn4s  = (const float*)d_in[21];
    const float* bn4b  = (const float*)d_in[22];
    const float* bn4m  = (const float*)d_in[23];
    const float* bn4v  = (const float*)d_in[24];

    float* ws  = (float*)d_ws;
    float* y   = ws + Y_OFF;
    float* P   = ws + Y_OFF;       // conv partials reuse depthnet buffer
    float* bev = ws + BEV_OFF;
    float* b0  = ws + B0_OFF;
    float* b1  = ws + B1_OFF;
    float* b2  = ws + B2_OFF;
    float* b3  = ws + B3_OFF;
    float* out = (float*)d_out;

    // zero atomic accumulator + padded conv buffers (borders) every call
    hipMemsetAsync(bev, 0, (size_t)(WS_END - BEV_OFF) * sizeof(float), stream);

    k_depthnet<<<dim3(88, 6), 256, 0, stream>>>(x, dnw, dnb, y);
    k_softmax<<<132, 256, 0, stream>>>(y);
    k_splat<<<(NPIX * DDEP + 255) / 256, 256, 0, stream>>>(y, rots, trans, bev);
    k_bev2chw<<<545, 256, 0, stream>>>(bev, b0);

    // conv1: 128 -> 128, 8 slices => 288 blocks
    k_conv_part<128, 8><<<dim3(9, 4, 8), 256, 0, stream>>>(b0, bw1, P, 128);
    k_conv_finish<8><<<(128 * NPIXO + 255) / 256, 256, 0, stream>>>(P, bn1s, bn1b, bn1m, bn1v, b1, 128, 1);
    // conv2: 128 -> 512, 4 slices => 576 blocks
    k_conv_part<128, 4><<<dim3(9, 16, 4), 256, 0, stream>>>(b1, bw2, P, 512);
    k_conv_finish<4><<<(512 * NPIXO + 255) / 256, 256, 0, stream>>>(P, bn2s, bn2b, bn2m, bn2v, b2, 512, 1);
    // conv3: 512 -> 512, 4 slices => 576 blocks
    k_conv_part<512, 4><<<dim3(9, 16, 4), 256, 0, stream>>>(b2, bw3, P, 512);
    k_conv_finish<4><<<(512 * NPIXO + 255) / 256, 256, 0, stream>>>(P, bn3s, bn3b, bn3m, bn3v, b3, 512, 1);
    // conv4: 512 -> 256, 8 slices => 576 blocks
    k_conv_part<512, 8><<<dim3(9, 8, 8), 256, 0, stream>>>(b3, bw4, P, 256);
    k_conv_finish<8><<<(256 * NPIXO + 255) / 256, 256, 0, stream>>>(P, bn4s, bn4b, bn4m, bn4v, out, 256, 0);
}

// Round 3
// 246.251 us; speedup vs baseline: 5.8569x; 1.8375x over previous
//
#include <hip/hip_runtime.h>
#include <math.h>

#define NCAM  6
#define INC   256
#define HH    56
#define WW    100
#define HW    5600
#define NPIX  33600
#define DDEP  41
#define CFEAT 64
#define NCH   105          // 41 depth + 64 feat
#define NXG   33
#define NYG   33
#define NZG   2
#define NVOX  2178         // 2*33*33
#define PADW  35
#define PADHW 1225         // 35*35
#define NPIXO 1089         // 33*33

typedef short bf16x8 __attribute__((ext_vector_type(8)));
typedef float f32x4  __attribute__((ext_vector_type(4)));

// ---- workspace layout (floats) ----
// Y region: depthnet output y until splat; then reused for conv3/conv4 weights
#define Y_OFF    0
#define YW_SZ    3538944                    // max(y 3,528,000 ; W3'+W4' 3,538,944)
#define W3H_OFF  (Y_OFF)                    // 9*512*512 shorts = 1,179,648 floats
#define W3L_OFF  (W3H_OFF + 1179648)
#define W4H_OFF  (W3L_OFF + 1179648)        // 9*256*512 shorts = 589,824 floats
#define W4L_OFF  (W4H_OFF + 589824)
#define W12_OFF  (Y_OFF + YW_SZ)
#define W1H_OFF  (W12_OFF)                  // 9*128*128 shorts = 73,728 floats
#define W1L_OFF  (W1H_OFF + 73728)
#define W2H_OFF  (W1L_OFF + 73728)          // 9*512*128 shorts = 294,912 floats
#define W2L_OFF  (W2H_OFF + 294912)
#define BEV_OFF  (W2L_OFF + 294912)
#define BEV_SZ   (NVOX * CFEAT)             // 139,392
#define A0H_OFF  (BEV_OFF + BEV_SZ)         // acts: [1225][CIN] bf16 (hi/lo)
#define A0L_OFF  (A0H_OFF + 78400)          // 1225*128 shorts = 78,400 floats
#define A1H_OFF  (A0L_OFF + 78400)
#define A1L_OFF  (A1H_OFF + 78400)
#define A2H_OFF  (A1L_OFF + 78400)          // 1225*512 shorts = 313,600 floats
#define A2L_OFF  (A2H_OFF + 313600)
#define A3H_OFF  (A2L_OFF + 313600)
#define A3L_OFF  (A3H_OFF + 313600)
#define P_OFF    (A3L_OFF + 313600)
#define P_SZ     2230272                    // max slices*1089*COUT (8*1089*256)
#define WS_END   (P_OFF + P_SZ)             // ~32.9 MB

__device__ __forceinline__ unsigned short f2bf_rn(float f) {
    unsigned u = __builtin_bit_cast(unsigned, f);
    unsigned r = (u + 0x7FFFu + ((u >> 16) & 1u)) >> 16;
    return (unsigned short)r;
}
__device__ __forceinline__ void split_bf(float f, unsigned short& h, unsigned short& l) {
    h = f2bf_rn(f);
    float hf = __builtin_bit_cast(float, (unsigned)h << 16);
    l = f2bf_rn(f - hf);
}

__device__ __forceinline__ void fma4(float4& a, float w, const float4& x) {
    a.x = fmaf(w, x.x, a.x);
    a.y = fmaf(w, x.y, a.y);
    a.z = fmaf(w, x.z, a.z);
    a.w = fmaf(w, x.w, a.w);
}

// ---------------- Stage 1: depthnet 1x1 conv (GEMM 33600 x 105 x 256) -------
__global__ __launch_bounds__(256) void k_depthnet(const float* __restrict__ x,
                                                  const float* __restrict__ dnw,
                                                  const float* __restrict__ dnb,
                                                  float* __restrict__ y)
{
    __shared__ float xs[64 * 64];     // [ci][px]
    __shared__ float wsh[105 * 68];   // [c][ci]
    const int t   = threadIdx.x;
    const int pxg = t & 15;
    const int cg  = t >> 4;
    const int n   = blockIdx.y;
    const int hw0 = blockIdx.x * 64;
    const int nrem = HW - hw0;
    const float* xn = x + (size_t)n * INC * HW;

    float4 acc[7];
#pragma unroll
    for (int i = 0; i < 7; ++i) acc[i] = make_float4(0.f, 0.f, 0.f, 0.f);

    for (int ci0 = 0; ci0 < INC; ci0 += 64) {
        __syncthreads();
        for (int i = t; i < 4096; i += 256) {
            int ci = i >> 6, px = i & 63;
            xs[i] = (px < nrem) ? xn[(size_t)(ci0 + ci) * HW + hw0 + px] : 0.f;
        }
        for (int i = t; i < 6720; i += 256) {
            int c = i >> 6, ci = i & 63;
            wsh[c * 68 + ci] = dnw[c * 256 + ci0 + ci];
        }
        __syncthreads();
#pragma unroll 4
        for (int ci = 0; ci < 64; ci += 4) {
            float4 xv0 = *(const float4*)&xs[(ci + 0) * 64 + pxg * 4];
            float4 xv1 = *(const float4*)&xs[(ci + 1) * 64 + pxg * 4];
            float4 xv2 = *(const float4*)&xs[(ci + 2) * 64 + pxg * 4];
            float4 xv3 = *(const float4*)&xs[(ci + 3) * 64 + pxg * 4];
#pragma unroll
            for (int cc = 0; cc < 7; ++cc) {
                int c = cc * 16 + cg;
                if (c < NCH) {
                    float4 wq = *(const float4*)&wsh[c * 68 + ci];
                    fma4(acc[cc], wq.x, xv0);
                    fma4(acc[cc], wq.y, xv1);
                    fma4(acc[cc], wq.z, xv2);
                    fma4(acc[cc], wq.w, xv3);
                }
            }
        }
    }
    const int px = pxg * 4;
    if (px < nrem) {
#pragma unroll
        for (int cc = 0; cc < 7; ++cc) {
            int c = cc * 16 + cg;
            if (c < NCH) {
                float b = dnb[c];
                float4 o = acc[cc];
                o.x += b; o.y += b; o.z += b; o.w += b;
                *(float4*)&y[((size_t)n * NCH + c) * HW + hw0 + px] = o;
            }
        }
    }
}

// ---------------- Stage 2: softmax over 41 depth channels (in place) -------
__global__ __launch_bounds__(256) void k_softmax(float* __restrict__ y)
{
    int p = blockIdx.x * 256 + threadIdx.x;
    if (p >= NPIX) return;
    int n = p / HW, hw = p - n * HW;
    float* base = y + (size_t)n * NCH * HW + hw;
    float v[DDEP];
    float m = -3.4e38f;
#pragma unroll
    for (int d = 0; d < DDEP; ++d) { v[d] = base[(size_t)d * HW]; m = fmaxf(m, v[d]); }
    float s = 0.f;
#pragma unroll
    for (int d = 0; d < DDEP; ++d) { v[d] = expf(v[d] - m); s += v[d]; }
#pragma unroll
    for (int d = 0; d < DDEP; ++d) base[(size_t)d * HW] = v[d] / s;
}

// ---------------- Stage 3: geometry + lift + splat (atomics) ---------------
__global__ __launch_bounds__(256) void k_splat(const float* __restrict__ y,
                                               const float* __restrict__ rots,
                                               const float* __restrict__ trans,
                                               float* __restrict__ bev)
{
    int idx = blockIdx.x * 256 + threadIdx.x;
    if (idx >= NPIX * DDEP) return;
    int di = idx / NPIX;
    int p  = idx - di * NPIX;
    int n = p / HW, hw = p - n * HW;
    int wi = hw % WW, hi = hw / WW;
    const float su = 1599.0f / 99.0f;
    const float sv = 899.0f / 55.0f;
    float u = __fmul_rn((float)wi, su);
    float v = __fmul_rn((float)hi, sv);
    const float* r = rots + n * 9;
    const float* tr = trans + n * 3;
    float dd  = 4.0f + (float)di;
    float pxv = __fmul_rn(u, dd);
    float pyv = __fmul_rn(v, dd);
    float gx = __fadd_rn(__fadd_rn(__fadd_rn(__fmul_rn(r[0], pxv), __fmul_rn(r[1], pyv)), __fmul_rn(r[2], dd)), tr[0]);
    float gy = __fadd_rn(__fadd_rn(__fadd_rn(__fmul_rn(r[3], pxv), __fmul_rn(r[4], pyv)), __fmul_rn(r[5], dd)), tr[1]);
    float gz = __fadd_rn(__fadd_rn(__fadd_rn(__fmul_rn(r[6], pxv), __fmul_rn(r[7], pyv)), __fmul_rn(r[8], dd)), tr[2]);
    int cx = (int)__fdiv_rn(__fadd_rn(gx, 50.0f), 3.0f);
    int cy = (int)__fdiv_rn(__fadd_rn(gy, 50.0f), 3.0f);
    int cz = (int)__fdiv_rn(__fadd_rn(gz, 5.0f), 3.0f);
    if (cx >= 0 && cx < NXG && cy >= 0 && cy < NYG && cz >= 0 && cz < NZG) {
        const float* dbase = y + (size_t)n * NCH * HW + hw;
        const float* fbase = dbase + (size_t)DDEP * HW;
        float dval = dbase[(size_t)di * HW];
        float* vp = bev + (size_t)((cz * NYG + cy) * NXG + cx) * CFEAT;
#pragma unroll 8
        for (int c = 0; c < CFEAT; ++c) {
            atomicAdd(vp + c, __fmul_rn(dval, fbase[(size_t)c * HW]));
        }
    }
}

// ---------------- weight prep: fp32 [CO][CI][3][3] -> bf16 h/l [9][CO][CI] --
__global__ __launch_bounds__(256) void k_wprep(const float* __restrict__ wgt,
                                               unsigned short* __restrict__ wh,
                                               unsigned short* __restrict__ wl,
                                               int COUT, int CIN)
{
    int i = blockIdx.x * 256 + threadIdx.x;
    int total = 9 * COUT * CIN;
    if (i >= total) return;
    int ci = i % CIN; int r = i / CIN; int co = r % COUT; int dydx = r / COUT;
    float w = wgt[((size_t)co * CIN + ci) * 9 + dydx];
    unsigned short h, l; split_bf(w, h, l);
    wh[i] = h; wl[i] = l;
}

// ---------------- bev [vox][c] -> act0 transposed [1225][128] bf16 h/l -----
__global__ __launch_bounds__(256) void k_bev2act(const float* __restrict__ bev,
                                                 unsigned short* __restrict__ ah,
                                                 unsigned short* __restrict__ al)
{
    int i = blockIdx.x * 256 + threadIdx.x;
    if (i >= NVOX * CFEAT) return;
    int vx = i >> 6, c = i & 63;
    int cz = vx / NPIXO, rem = vx - cz * NPIXO;
    int yy = rem / NXG, xx = rem - yy * NXG;
    int ch = c * 2 + cz;
    int pos = (yy + 1) * PADW + xx + 1;
    unsigned short h, l; split_bf(bev[i], h, l);
    ah[pos * 128 + ch] = h;
    al[pos * 128 + ch] = l;
}

// ---------------- MFMA 3x3 conv partials (split-bf16, 3-term) --------------
// block: 256 thr = 4 waves; wave computes 16co x 132px (9 col-tiles of 16x16).
// grid: (9 row-tiles of 4 output rows, COUT/64, SLICES)
// B in LDS: [pos 0..209][8 slots x 8 bf16]; slots 0-3 hi ci-groups, 4-7 lo;
// stored at slot^(pos&7)  => banks spread, ~2 lanes/bank on reads.
template<int CIN, int COUT, int SL>
__global__ __launch_bounds__(256) void k_conv_mfma(const unsigned short* __restrict__ ah,
                                                   const unsigned short* __restrict__ al,
                                                   const unsigned short* __restrict__ wh,
                                                   const unsigned short* __restrict__ wl,
                                                   float* __restrict__ P)
{
    constexpr int CI_PER = CIN / SL;
    __shared__ unsigned short bs[210 * 64];   // 26.9 KB
    const int t  = threadIdx.x;
    const int w  = t >> 6;
    const int l  = t & 63;
    const int lp = l & 15;
    const int q  = l >> 4;
    const int y0  = blockIdx.x * 4;
    const int cob = blockIdx.y * 64 + w * 16;
    const int sl  = blockIdx.z;
    const int ci_base = sl * CI_PER;

    int  pos0[9];
    bool vld[9];
#pragma unroll
    for (int ct = 0; ct < 9; ++ct) {
        int tp = ct * 16 + lp;
        int r = tp / 33, c = tp - r * 33;
        bool v = (tp < 132) && (y0 + r < 33);
        vld[ct]  = v;
        pos0[ct] = v ? (r * 35 + c) : 0;
    }

    f32x4 acc[9];
#pragma unroll
    for (int ct = 0; ct < 9; ++ct) acc[ct] = (f32x4){0.f, 0.f, 0.f, 0.f};

    for (int chk = 0; chk < CI_PER; chk += 32) {
        const int ci0 = ci_base + chk;
        __syncthreads();
        for (int i = t; i < 210 * 8; i += 256) {
            int pos = i >> 3, s = i & 7;
            int gpos = y0 * 35 + pos;
            const unsigned short* src = (s < 4) ? ah : al;
            int sp = s ^ (pos & 7);
            uint4 val = make_uint4(0u, 0u, 0u, 0u);
            if (gpos < PADHW)
                val = *(const uint4*)&src[(size_t)gpos * CIN + ci0 + (s & 3) * 8];
            *(uint4*)&bs[pos * 64 + sp * 8] = val;
        }
        __syncthreads();

#pragma unroll 3
        for (int dydx = 0; dydx < 9; ++dydx) {
            int dy = dydx / 3, dx = dydx - dy * 3;
            int off = dy * 35 + dx;
            const size_t abase = ((size_t)dydx * COUT + cob + lp) * CIN + ci0 + q * 8;
            bf16x8 Ah = *(const bf16x8*)&wh[abase];
            bf16x8 Al = *(const bf16x8*)&wl[abase];
#pragma unroll
            for (int ct = 0; ct < 9; ++ct) {
                int pos = pos0[ct] + off;
                int sph = q ^ (pos & 7);
                bf16x8 Bh = *(const bf16x8*)&bs[pos * 64 + sph * 8];
                bf16x8 Bl = *(const bf16x8*)&bs[pos * 64 + (sph ^ 4) * 8];
                acc[ct] = __builtin_amdgcn_mfma_f32_16x16x32_bf16(Ah, Bh, acc[ct], 0, 0, 0);
                acc[ct] = __builtin_amdgcn_mfma_f32_16x16x32_bf16(Ah, Bl, acc[ct], 0, 0, 0);
                acc[ct] = __builtin_amdgcn_mfma_f32_16x16x32_bf16(Al, Bh, acc[ct], 0, 0, 0);
            }
        }
    }

    // store P[sl][gp][co]; D layout: col(px)=lane&15, row(co)=q*4+reg
#pragma unroll
    for (int ct = 0; ct < 9; ++ct) {
        if (!vld[ct]) continue;
        int gp = y0 * 33 + ct * 16 + lp;
        float* dst = P + ((size_t)sl * NPIXO + gp) * COUT + cob + q * 4;
        *(f32x4*)dst = acc[ct];
    }
}

// ---------------- reduce slices + BN + ReLU -> next act (or final out) -----
template<int SL>
__global__ __launch_bounds__(256) void k_finish(const float* __restrict__ P,
                                                const float* __restrict__ bns,
                                                const float* __restrict__ bnb,
                                                const float* __restrict__ bnm,
                                                const float* __restrict__ bnv,
                                                unsigned short* __restrict__ oh,
                                                unsigned short* __restrict__ ol,
                                                float* __restrict__ outf,
                                                int COUT)
{
    int i = blockIdx.x * 256 + threadIdx.x;
    if (i >= COUT * NPIXO) return;
    int co = i % COUT, p = i / COUT;
    float s = 0.f;
#pragma unroll
    for (int sl = 0; sl < SL; ++sl)
        s += P[((size_t)sl * NPIXO + p) * COUT + co];
    float sc = bns[co] / sqrtf(bnv[co] + 1e-5f);
    float bi = bnb[co] - bnm[co] * sc;
    float rv = fmaxf(fmaf(s, sc, bi), 0.f);
    if (outf) {
        outf[(size_t)co * NPIXO + p] = rv;
    } else {
        int yy = p / NXG, xx = p - yy * NXG;
        int pos = (yy + 1) * PADW + xx + 1;
        unsigned short h, lo; split_bf(rv, h, lo);
        oh[(size_t)pos * COUT + co] = h;
        ol[(size_t)pos * COUT + co] = lo;
    }
}

extern "C" void kernel_launch(void* const* d_in, const int* in_sizes, int n_in,
                              void* d_out, int out_size, void* d_ws, size_t ws_size,
                              hipStream_t stream)
{
    const float* x     = (const float*)d_in[0];
    const float* rots  = (const float*)d_in[1];
    const float* trans = (const float*)d_in[2];
    const float* dnw   = (const float*)d_in[3];
    const float* dnb   = (const float*)d_in[4];
    const float* bw1   = (const float*)d_in[5];
    const float* bn1s  = (const float*)d_in[6];
    const float* bn1b  = (const float*)d_in[7];
    const float* bn1m  = (const float*)d_in[8];
    const float* bn1v  = (const float*)d_in[9];
    const float* bw2   = (const float*)d_in[10];
    const float* bn2s  = (const float*)d_in[11];
    const float* bn2b  = (const float*)d_in[12];
    const float* bn2m  = (const float*)d_in[13];
    const float* bn2v  = (const float*)d_in[14];
    const float* bw3   = (const float*)d_in[15];
    const float* bn3s  = (const float*)d_in[16];
    const float* bn3b  = (const float*)d_in[17];
    const float* bn3m  = (const float*)d_in[18];
    const float* bn3v  = (const float*)d_in[19];
    const float* bw4   = (const float*)d_in[20];
    const float* bn4s  = (const float*)d_in[21];
    const float* bn4b  = (const float*)d_in[22];
    const float* bn4m  = (const float*)d_in[23];
    const float* bn4v  = (const float*)d_in[24];

    float* ws  = (float*)d_ws;
    float* y   = ws + Y_OFF;
    float* bev = ws + BEV_OFF;
    float* P   = ws + P_OFF;
    unsigned short* w1h = (unsigned short*)(ws + W1H_OFF);
    unsigned short* w1l = (unsigned short*)(ws + W1L_OFF);
    unsigned short* w2h = (unsigned short*)(ws + W2H_OFF);
    unsigned short* w2l = (unsigned short*)(ws + W2L_OFF);
    unsigned short* w3h = (unsigned short*)(ws + W3H_OFF);
    unsigned short* w3l = (unsigned short*)(ws + W3L_OFF);
    unsigned short* w4h = (unsigned short*)(ws + W4H_OFF);
    unsigned short* w4l = (unsigned short*)(ws + W4L_OFF);
    unsigned short* a0h = (unsigned short*)(ws + A0H_OFF);
    unsigned short* a0l = (unsigned short*)(ws + A0L_OFF);
    unsigned short* a1h = (unsigned short*)(ws + A1H_OFF);
    unsigned short* a1l = (unsigned short*)(ws + A1L_OFF);
    unsigned short* a2h = (unsigned short*)(ws + A2H_OFF);
    unsigned short* a2l = (unsigned short*)(ws + A2L_OFF);
    unsigned short* a3h = (unsigned short*)(ws + A3H_OFF);
    unsigned short* a3l = (unsigned short*)(ws + A3L_OFF);
    float* out = (float*)d_out;

    // zero bev accumulator + act buffers (their padded borders must be 0)
    hipMemsetAsync(bev, 0, (size_t)(P_OFF - BEV_OFF) * sizeof(float), stream);

    k_depthnet<<<dim3(88, 6), 256, 0, stream>>>(x, dnw, dnb, y);
    k_softmax<<<132, 256, 0, stream>>>(y);
    k_splat<<<(NPIX * DDEP + 255) / 256, 256, 0, stream>>>(y, rots, trans, bev);

    // weight prep (w3/w4 reuse the y region -> must be after splat)
    k_wprep<<<(9 * 128 * 128 + 255) / 256, 256, 0, stream>>>(bw1, w1h, w1l, 128, 128);
    k_wprep<<<(9 * 512 * 128 + 255) / 256, 256, 0, stream>>>(bw2, w2h, w2l, 512, 128);
    k_wprep<<<(9 * 512 * 512 + 255) / 256, 256, 0, stream>>>(bw3, w3h, w3l, 512, 512);
    k_wprep<<<(9 * 256 * 512 + 255) / 256, 256, 0, stream>>>(bw4, w4h, w4l, 256, 512);

    k_bev2act<<<(NVOX * CFEAT + 255) / 256, 256, 0, stream>>>(bev, a0h, a0l);

    // conv1: 128 -> 128
    k_conv_mfma<128, 128, 4><<<dim3(9, 2, 4), 256, 0, stream>>>(a0h, a0l, w1h, w1l, P);
    k_finish<4><<<(128 * NPIXO + 255) / 256, 256, 0, stream>>>(P, bn1s, bn1b, bn1m, bn1v, a1h, a1l, nullptr, 128);
    // conv2: 128 -> 512
    k_conv_mfma<128, 512, 4><<<dim3(9, 8, 4), 256, 0, stream>>>(a1h, a1l, w2h, w2l, P);
    k_finish<4><<<(512 * NPIXO + 255) / 256, 256, 0, stream>>>(P, bn2s, bn2b, bn2m, bn2v, a2h, a2l, nullptr, 512);
    // conv3: 512 -> 512
    k_conv_mfma<512, 512, 4><<<dim3(9, 8, 4), 256, 0, stream>>>(a2h, a2l, w3h, w3l, P);
    k_finish<4><<<(512 * NPIXO + 255) / 256, 256, 0, stream>>>(P, bn3s, bn3b, bn3m, bn3v, a3h, a3l, nullptr, 512);
    // conv4: 512 -> 256 (final, fp32 out [256][33][33])
    k_conv_mfma<512, 256, 8><<<dim3(9, 4, 8), 256, 0, stream>>>(a3h, a3l, w4h, w4l, P);
    k_finish<8><<<(256 * NPIXO + 255) / 256, 256, 0, stream>>>(P, bn4s, bn4b, bn4m, bn4v, nullptr, nullptr, out, 256);
}

// Round 4
// 214.675 us; speedup vs baseline: 6.7184x; 1.1471x over previous
//
#include <hip/hip_runtime.h>
#include <math.h>

#define NCAM  6
#define INC   256
#define HH    56
#define WW    100
#define HW    5600
#define NPIX  33600
#define DDEP  41
#define CFEAT 64
#define NCH   105          // 41 depth + 64 feat
#define NXG   33
#define NYG   33
#define NZG   2
#define NVOX  2178         // 2*33*33
#define PADW  35
#define PADHW 1225         // 35*35
#define NPIXO 1089         // 33*33

typedef short bf16x8 __attribute__((ext_vector_type(8)));
typedef float f32x4  __attribute__((ext_vector_type(4)));

// ---- workspace layout (floats) ----
// Y region: depthnet output y until splat; then reused for conv3/conv4 weights
#define Y_OFF    0
#define YW_SZ    3538944                    // max(y 3,528,000 ; W3'+W4' 3,538,944)
#define W3H_OFF  (Y_OFF)                    // 9*512*512 shorts = 1,179,648 floats
#define W3L_OFF  (W3H_OFF + 1179648)
#define W4H_OFF  (W3L_OFF + 1179648)        // 9*256*512 shorts = 589,824 floats
#define W4L_OFF  (W4H_OFF + 589824)
#define W12_OFF  (Y_OFF + YW_SZ)
#define W1H_OFF  (W12_OFF)                  // 9*128*128 shorts = 73,728 floats
#define W1L_OFF  (W1H_OFF + 73728)
#define W2H_OFF  (W1L_OFF + 73728)
#define W2L_OFF  (W2H_OFF + 294912)
#define BEV_OFF  (W2L_OFF + 294912)
#define BEV_SZ   (NVOX * CFEAT)             // 139,392
#define A0H_OFF  (BEV_OFF + BEV_SZ)         // acts: [1225][CIN] bf16 (hi/lo)
#define A0L_OFF  (A0H_OFF + 78400)
#define A1H_OFF  (A0L_OFF + 78400)
#define A1L_OFF  (A1H_OFF + 78400)
#define A2H_OFF  (A1L_OFF + 78400)          // 1225*512 shorts = 313,600 floats
#define A2L_OFF  (A2H_OFF + 313600)
#define A3H_OFF  (A2L_OFF + 313600)
#define A3L_OFF  (A3H_OFF + 313600)
#define P_OFF    (A3L_OFF + 313600)
#define P_SZ     2230272                    // max slices*1089*COUT (8*1089*256)
#define WS_END   (P_OFF + P_SZ)             // ~32.9 MB
// depthnet weights live at the START of the P region (dead until conv1):
// wdh/wdl each 112*256 shorts = 14336 floats
#define WDH_OFF  (P_OFF)
#define WDL_OFF  (P_OFF + 14336)

__device__ __forceinline__ unsigned short f2bf_rn(float f) {
    unsigned u = __builtin_bit_cast(unsigned, f);
    unsigned r = (u + 0x7FFFu + ((u >> 16) & 1u)) >> 16;
    return (unsigned short)r;
}
__device__ __forceinline__ void split_bf(float f, unsigned short& h, unsigned short& l) {
    h = f2bf_rn(f);
    float hf = __builtin_bit_cast(float, (unsigned)h << 16);
    l = f2bf_rn(f - hf);
}

// ---------------- depthnet weight prep: [105][256] -> [112][256] h/l -------
__global__ __launch_bounds__(256) void k_wprep_dn(const float* __restrict__ dnw,
                                                  unsigned short* __restrict__ wdh,
                                                  unsigned short* __restrict__ wdl)
{
    int i = blockIdx.x * 256 + threadIdx.x;
    if (i >= 112 * 256) return;
    int co = i >> 8, ci = i & 255;
    float w = (co < NCH) ? dnw[co * 256 + ci] : 0.f;
    unsigned short h, l; split_bf(w, h, l);
    wdh[i] = h; wdl[i] = l;
}

// ---------------- Stage 1: depthnet 1x1 conv via MFMA (split-bf16) ---------
// GEMM: M=105(pad112) co, N=5600 px/cam, K=256 ci.  Block = 64 px, 4 waves;
// wave w owns px-subtile w (16 px) x all 7 co-tiles.
__global__ __launch_bounds__(256) void k_depthnet_mfma(const float* __restrict__ x,
                                                       const unsigned short* __restrict__ wdh,
                                                       const unsigned short* __restrict__ wdl,
                                                       const float* __restrict__ dnb,
                                                       float* __restrict__ y)
{
    __shared__ float xs[32][65];              // fp32 staging, pad 65 (2-way max)
    __shared__ unsigned short bs[64 * 64];    // [px][8 slots x 8 bf16], XOR-swizzled
    const int t  = threadIdx.x;
    const int w  = t >> 6;
    const int l  = t & 63;
    const int lp = l & 15;
    const int q  = l >> 4;
    const int n   = blockIdx.y;
    const int hw0 = blockIdx.x * 64;
    const int nrem = HW - hw0;                // 64 or 32
    const float* xn = x + (size_t)n * INC * HW;
    const int px = w * 16 + lp;               // this lane's B/D column (0..63)
    const int spx = t >> 2, ss = t & 3;       // converter thread's (px, ci-slot)

    f32x4 acc[7];
#pragma unroll
    for (int ct = 0; ct < 7; ++ct) acc[ct] = (f32x4){0.f, 0.f, 0.f, 0.f};

    for (int ci0 = 0; ci0 < INC; ci0 += 32) {
        // stage fp32 tile [32 ci][64 px] coalesced
        for (int i = t; i < 2048; i += 256) {
            int ci = i >> 6, p = i & 63;
            xs[ci][p] = (p < nrem) ? xn[(size_t)(ci0 + ci) * HW + hw0 + p] : 0.f;
        }
        __syncthreads();
        // convert: thread (spx, ss) splits 8 values, writes hi+lo uint4 slots
        {
            unsigned short vh[8], vl[8];
            int cib = ss * 8;
#pragma unroll
            for (int j = 0; j < 8; ++j) split_bf(xs[cib + j][spx], vh[j], vl[j]);
            int sw = ss ^ (spx & 7);
            *(uint4*)&bs[spx * 64 + sw * 8]       = *(const uint4*)vh;
            *(uint4*)&bs[spx * 64 + (sw ^ 4) * 8] = *(const uint4*)vl;
        }
        __syncthreads();
        // MFMA: 7 co-tiles x 3-term split
        const int sph = q ^ (px & 7);
        bf16x8 Bh = *(const bf16x8*)&bs[px * 64 + sph * 8];
        bf16x8 Bl = *(const bf16x8*)&bs[px * 64 + (sph ^ 4) * 8];
#pragma unroll
        for (int ct = 0; ct < 7; ++ct) {
            const size_t ab = (size_t)(ct * 16 + lp) * 256 + ci0 + q * 8;
            bf16x8 Ah = *(const bf16x8*)&wdh[ab];
            bf16x8 Al = *(const bf16x8*)&wdl[ab];
            acc[ct] = __builtin_amdgcn_mfma_f32_16x16x32_bf16(Ah, Bh, acc[ct], 0, 0, 0);
            acc[ct] = __builtin_amdgcn_mfma_f32_16x16x32_bf16(Ah, Bl, acc[ct], 0, 0, 0);
            acc[ct] = __builtin_amdgcn_mfma_f32_16x16x32_bf16(Al, Bh, acc[ct], 0, 0, 0);
        }
        __syncthreads();   // bs/xs reuse next iteration
    }
    // epilogue: D col(px)=lane&15, row(co within tile)=q*4+reg
    if (px < nrem) {
#pragma unroll
        for (int ct = 0; ct < 7; ++ct) {
#pragma unroll
            for (int j = 0; j < 4; ++j) {
                int co = ct * 16 + q * 4 + j;
                if (co < NCH)
                    y[((size_t)n * NCH + co) * HW + hw0 + px] = acc[ct][j] + dnb[co];
            }
        }
    }
}

// ---------------- Stage 2: softmax over 41 depth channels (in place) -------
__global__ __launch_bounds__(256) void k_softmax(float* __restrict__ y)
{
    int p = blockIdx.x * 256 + threadIdx.x;
    if (p >= NPIX) return;
    int n = p / HW, hw = p - n * HW;
    float* base = y + (size_t)n * NCH * HW + hw;
    float v[DDEP];
    float m = -3.4e38f;
#pragma unroll
    for (int d = 0; d < DDEP; ++d) { v[d] = base[(size_t)d * HW]; m = fmaxf(m, v[d]); }
    float s = 0.f;
#pragma unroll
    for (int d = 0; d < DDEP; ++d) { v[d] = expf(v[d] - m); s += v[d]; }
#pragma unroll
    for (int d = 0; d < DDEP; ++d) base[(size_t)d * HW] = v[d] / s;
}

// ---------------- Stage 3: geometry + lift + splat (atomics) ---------------
__global__ __launch_bounds__(256) void k_splat(const float* __restrict__ y,
                                               const float* __restrict__ rots,
                                               const float* __restrict__ trans,
                                               float* __restrict__ bev)
{
    int idx = blockIdx.x * 256 + threadIdx.x;
    if (idx >= NPIX * DDEP) return;
    int di = idx / NPIX;
    int p  = idx - di * NPIX;
    int n = p / HW, hw = p - n * HW;
    int wi = hw % WW, hi = hw / WW;
    const float su = 1599.0f / 99.0f;
    const float sv = 899.0f / 55.0f;
    float u = __fmul_rn((float)wi, su);
    float v = __fmul_rn((float)hi, sv);
    const float* r = rots + n * 9;
    const float* tr = trans + n * 3;
    float dd  = 4.0f + (float)di;
    float pxv = __fmul_rn(u, dd);
    float pyv = __fmul_rn(v, dd);
    float gx = __fadd_rn(__fadd_rn(__fadd_rn(__fmul_rn(r[0], pxv), __fmul_rn(r[1], pyv)), __fmul_rn(r[2], dd)), tr[0]);
    float gy = __fadd_rn(__fadd_rn(__fadd_rn(__fmul_rn(r[3], pxv), __fmul_rn(r[4], pyv)), __fmul_rn(r[5], dd)), tr[1]);
    float gz = __fadd_rn(__fadd_rn(__fadd_rn(__fmul_rn(r[6], pxv), __fmul_rn(r[7], pyv)), __fmul_rn(r[8], dd)), tr[2]);
    int cx = (int)__fdiv_rn(__fadd_rn(gx, 50.0f), 3.0f);
    int cy = (int)__fdiv_rn(__fadd_rn(gy, 50.0f), 3.0f);
    int cz = (int)__fdiv_rn(__fadd_rn(gz, 5.0f), 3.0f);
    if (cx >= 0 && cx < NXG && cy >= 0 && cy < NYG && cz >= 0 && cz < NZG) {
        const float* dbase = y + (size_t)n * NCH * HW + hw;
        const float* fbase = dbase + (size_t)DDEP * HW;
        float dval = dbase[(size_t)di * HW];
        float* vp = bev + (size_t)((cz * NYG + cy) * NXG + cx) * CFEAT;
#pragma unroll 8
        for (int c = 0; c < CFEAT; ++c) {
            atomicAdd(vp + c, __fmul_rn(dval, fbase[(size_t)c * HW]));
        }
    }
}

// ---------------- conv weight prep: fp32 [CO][CI][3][3] -> h/l [9][CO][CI] -
__global__ __launch_bounds__(256) void k_wprep(const float* __restrict__ wgt,
                                               unsigned short* __restrict__ wh,
                                               unsigned short* __restrict__ wl,
                                               int COUT, int CIN)
{
    int i = blockIdx.x * 256 + threadIdx.x;
    int total = 9 * COUT * CIN;
    if (i >= total) return;
    int ci = i % CIN; int r = i / CIN; int co = r % COUT; int dydx = r / COUT;
    float w = wgt[((size_t)co * CIN + ci) * 9 + dydx];
    unsigned short h, l; split_bf(w, h, l);
    wh[i] = h; wl[i] = l;
}

// ---------------- bev [vox][c] -> act0 transposed [1225][128] bf16 h/l -----
__global__ __launch_bounds__(256) void k_bev2act(const float* __restrict__ bev,
                                                 unsigned short* __restrict__ ah,
                                                 unsigned short* __restrict__ al)
{
    int i = blockIdx.x * 256 + threadIdx.x;
    if (i >= NVOX * CFEAT) return;
    int vx = i >> 6, c = i & 63;
    int cz = vx / NPIXO, rem = vx - cz * NPIXO;
    int yy = rem / NXG, xx = rem - yy * NXG;
    int ch = c * 2 + cz;
    int pos = (yy + 1) * PADW + xx + 1;
    unsigned short h, l; split_bf(bev[i], h, l);
    ah[pos * 128 + ch] = h;
    al[pos * 128 + ch] = l;
}

// ---------------- MFMA 3x3 conv partials (split-bf16, 3-term) --------------
template<int CIN, int COUT, int SL>
__global__ __launch_bounds__(256) void k_conv_mfma(const unsigned short* __restrict__ ah,
                                                   const unsigned short* __restrict__ al,
                                                   const unsigned short* __restrict__ wh,
                                                   const unsigned short* __restrict__ wl,
                                                   float* __restrict__ P)
{
    constexpr int CI_PER = CIN / SL;
    __shared__ unsigned short bs[210 * 64];   // 26.9 KB
    const int t  = threadIdx.x;
    const int w  = t >> 6;
    const int l  = t & 63;
    const int lp = l & 15;
    const int q  = l >> 4;
    const int y0  = blockIdx.x * 4;
    const int cob = blockIdx.y * 64 + w * 16;
    const int sl  = blockIdx.z;
    const int ci_base = sl * CI_PER;

    int  pos0[9];
    bool vld[9];
#pragma unroll
    for (int ct = 0; ct < 9; ++ct) {
        int tp = ct * 16 + lp;
        int r = tp / 33, c = tp - r * 33;
        bool v = (tp < 132) && (y0 + r < 33);
        vld[ct]  = v;
        pos0[ct] = v ? (r * 35 + c) : 0;
    }

    f32x4 acc[9];
#pragma unroll
    for (int ct = 0; ct < 9; ++ct) acc[ct] = (f32x4){0.f, 0.f, 0.f, 0.f};

    for (int chk = 0; chk < CI_PER; chk += 32) {
        const int ci0 = ci_base + chk;
        __syncthreads();
        for (int i = t; i < 210 * 8; i += 256) {
            int pos = i >> 3, s = i & 7;
            int gpos = y0 * 35 + pos;
            const unsigned short* src = (s < 4) ? ah : al;
            int sp = s ^ (pos & 7);
            uint4 val = make_uint4(0u, 0u, 0u, 0u);
            if (gpos < PADHW)
                val = *(const uint4*)&src[(size_t)gpos * CIN + ci0 + (s & 3) * 8];
            *(uint4*)&bs[pos * 64 + sp * 8] = val;
        }
        __syncthreads();

#pragma unroll 3
        for (int dydx = 0; dydx < 9; ++dydx) {
            int dy = dydx / 3, dx = dydx - dy * 3;
            int off = dy * 35 + dx;
            const size_t abase = ((size_t)dydx * COUT + cob + lp) * CIN + ci0 + q * 8;
            bf16x8 Ah = *(const bf16x8*)&wh[abase];
            bf16x8 Al = *(const bf16x8*)&wl[abase];
#pragma unroll
            for (int ct = 0; ct < 9; ++ct) {
                int pos = pos0[ct] + off;
                int sph = q ^ (pos & 7);
                bf16x8 Bh = *(const bf16x8*)&bs[pos * 64 + sph * 8];
                bf16x8 Bl = *(const bf16x8*)&bs[pos * 64 + (sph ^ 4) * 8];
                acc[ct] = __builtin_amdgcn_mfma_f32_16x16x32_bf16(Ah, Bh, acc[ct], 0, 0, 0);
                acc[ct] = __builtin_amdgcn_mfma_f32_16x16x32_bf16(Ah, Bl, acc[ct], 0, 0, 0);
                acc[ct] = __builtin_amdgcn_mfma_f32_16x16x32_bf16(Al, Bh, acc[ct], 0, 0, 0);
            }
        }
    }

#pragma unroll
    for (int ct = 0; ct < 9; ++ct) {
        if (!vld[ct]) continue;
        int gp = y0 * 33 + ct * 16 + lp;
        float* dst = P + ((size_t)sl * NPIXO + gp) * COUT + cob + q * 4;
        *(f32x4*)dst = acc[ct];
    }
}

// ---------------- reduce slices + BN + ReLU -> next act (or final out) -----
template<int SL>
__global__ __launch_bounds__(256) void k_finish(const float* __restrict__ P,
                                                const float* __restrict__ bns,
                                                const float* __restrict__ bnb,
                                                const float* __restrict__ bnm,
                                                const float* __restrict__ bnv,
                                                unsigned short* __restrict__ oh,
                                                unsigned short* __restrict__ ol,
                                                float* __restrict__ outf,
                                                int COUT)
{
    int i = blockIdx.x * 256 + threadIdx.x;
    if (i >= COUT * NPIXO) return;
    int co = i % COUT, p = i / COUT;
    float s = 0.f;
#pragma unroll
    for (int sl = 0; sl < SL; ++sl)
        s += P[((size_t)sl * NPIXO + p) * COUT + co];
    float sc = bns[co] / sqrtf(bnv[co] + 1e-5f);
    float bi = bnb[co] - bnm[co] * sc;
    float rv = fmaxf(fmaf(s, sc, bi), 0.f);
    if (outf) {
        outf[(size_t)co * NPIXO + p] = rv;
    } else {
        int yy = p / NXG, xx = p - yy * NXG;
        int pos = (yy + 1) * PADW + xx + 1;
        unsigned short h, lo; split_bf(rv, h, lo);
        oh[(size_t)pos * COUT + co] = h;
        ol[(size_t)pos * COUT + co] = lo;
    }
}

extern "C" void kernel_launch(void* const* d_in, const int* in_sizes, int n_in,
                              void* d_out, int out_size, void* d_ws, size_t ws_size,
                              hipStream_t stream)
{
    const float* x     = (const float*)d_in[0];
    const float* rots  = (const float*)d_in[1];
    const float* trans = (const float*)d_in[2];
    const float* dnw   = (const float*)d_in[3];
    const float* dnb   = (const float*)d_in[4];
    const float* bw1   = (const float*)d_in[5];
    const float* bn1s  = (const float*)d_in[6];
    const float* bn1b  = (const float*)d_in[7];
    const float* bn1m  = (const float*)d_in[8];
    const float* bn1v  = (const float*)d_in[9];
    const float* bw2   = (const float*)d_in[10];
    const float* bn2s  = (const float*)d_in[11];
    const float* bn2b  = (const float*)d_in[12];
    const float* bn2m  = (const float*)d_in[13];
    const float* bn2v  = (const float*)d_in[14];
    const float* bw3   = (const float*)d_in[15];
    const float* bn3s  = (const float*)d_in[16];
    const float* bn3b  = (const float*)d_in[17];
    const float* bn3m  = (const float*)d_in[18];
    const float* bn3v  = (const float*)d_in[19];
    const float* bw4   = (const float*)d_in[20];
    const float* bn4s  = (const float*)d_in[21];
    const float* bn4b  = (const float*)d_in[22];
    const float* bn4m  = (const float*)d_in[23];
    const float* bn4v  = (const float*)d_in[24];

    float* ws  = (float*)d_ws;
    float* y   = ws + Y_OFF;
    float* bev = ws + BEV_OFF;
    float* P   = ws + P_OFF;
    unsigned short* w1h = (unsigned short*)(ws + W1H_OFF);
    unsigned short* w1l = (unsigned short*)(ws + W1L_OFF);
    unsigned short* w2h = (unsigned short*)(ws + W2H_OFF);
    unsigned short* w2l = (unsigned short*)(ws + W2L_OFF);
    unsigned short* w3h = (unsigned short*)(ws + W3H_OFF);
    unsigned short* w3l = (unsigned short*)(ws + W3L_OFF);
    unsigned short* w4h = (unsigned short*)(ws + W4H_OFF);
    unsigned short* w4l = (unsigned short*)(ws + W4L_OFF);
    unsigned short* a0h = (unsigned short*)(ws + A0H_OFF);
    unsigned short* a0l = (unsigned short*)(ws + A0L_OFF);
    unsigned short* a1h = (unsigned short*)(ws + A1H_OFF);
    unsigned short* a1l = (unsigned short*)(ws + A1L_OFF);
    unsigned short* a2h = (unsigned short*)(ws + A2H_OFF);
    unsigned short* a2l = (unsigned short*)(ws + A2L_OFF);
    unsigned short* a3h = (unsigned short*)(ws + A3H_OFF);
    unsigned short* a3l = (unsigned short*)(ws + A3L_OFF);
    unsigned short* wdh = (unsigned short*)(ws + WDH_OFF);
    unsigned short* wdl = (unsigned short*)(ws + WDL_OFF);
    float* out = (float*)d_out;

    // zero bev accumulator + act buffers (their padded borders must be 0)
    hipMemsetAsync(bev, 0, (size_t)(P_OFF - BEV_OFF) * sizeof(float), stream);

    // depthnet: weight prep (lives in P region, dead until conv1) + MFMA GEMM
    k_wprep_dn<<<(112 * 256 + 255) / 256, 256, 0, stream>>>(dnw, wdh, wdl);
    k_depthnet_mfma<<<dim3(88, 6), 256, 0, stream>>>(x, wdh, wdl, dnb, y);
    k_softmax<<<132, 256, 0, stream>>>(y);
    k_splat<<<(NPIX * DDEP + 255) / 256, 256, 0, stream>>>(y, rots, trans, bev);

    // conv weight prep (w3/w4 reuse the y region -> must be after splat)
    k_wprep<<<(9 * 128 * 128 + 255) / 256, 256, 0, stream>>>(bw1, w1h, w1l, 128, 128);
    k_wprep<<<(9 * 512 * 128 + 255) / 256, 256, 0, stream>>>(bw2, w2h, w2l, 512, 128);
    k_wprep<<<(9 * 512 * 512 + 255) / 256, 256, 0, stream>>>(bw3, w3h, w3l, 512, 512);
    k_wprep<<<(9 * 256 * 512 + 255) / 256, 256, 0, stream>>>(bw4, w4h, w4l, 256, 512);

    k_bev2act<<<(NVOX * CFEAT + 255) / 256, 256, 0, stream>>>(bev, a0h, a0l);

    // conv1: 128 -> 128
    k_conv_mfma<128, 128, 4><<<dim3(9, 2, 4), 256, 0, stream>>>(a0h, a0l, w1h, w1l, P);
    k_finish<4><<<(128 * NPIXO + 255) / 256, 256, 0, stream>>>(P, bn1s, bn1b, bn1m, bn1v, a1h, a1l, nullptr, 128);
    // conv2: 128 -> 512
    k_conv_mfma<128, 512, 4><<<dim3(9, 8, 4), 256, 0, stream>>>(a1h, a1l, w2h, w2l, P);
    k_finish<4><<<(512 * NPIXO + 255) / 256, 256, 0, stream>>>(P, bn2s, bn2b, bn2m, bn2v, a2h, a2l, nullptr, 512);
    // conv3: 512 -> 512
    k_conv_mfma<512, 512, 4><<<dim3(9, 8, 4), 256, 0, stream>>>(a2h, a2l, w3h, w3l, P);
    k_finish<4><<<(512 * NPIXO + 255) / 256, 256, 0, stream>>>(P, bn3s, bn3b, bn3m, bn3v, a3h, a3l, nullptr, 512);
    // conv4: 512 -> 256 (final, fp32 out [256][33][33])
    k_conv_mfma<512, 256, 8><<<dim3(9, 4, 8), 256, 0, stream>>>(a3h, a3l, w4h, w4l, P);
    k_finish<8><<<(256 * NPIXO + 255) / 256, 256, 0, stream>>>(P, bn4s, bn4b, bn4m, bn4v, nullptr, nullptr, out, 256);
}

// Round 5
// 201.455 us; speedup vs baseline: 7.1592x; 1.0656x over previous
//
#include <hip/hip_runtime.h>
#include <math.h>

#define NCAM  6
#define INC   256
#define HH    56
#define WW    100
#define HW    5600
#define NPIX  33600
#define DDEP  41
#define CFEAT 64
#define NCH   105          // 41 depth + 64 feat
#define NXG   33
#define NYG   33
#define NZG   2
#define NVOX  2178         // 2*33*33
#define PADW  35
#define PADHW 1225         // 35*35
#define NPIXO 1089         // 33*33

typedef short bf16x8 __attribute__((ext_vector_type(8)));
typedef float f32x4  __attribute__((ext_vector_type(4)));

// ---- workspace layout (floats) ----
// Y region: depthnet output y until splat; then reused for conv3/conv4 weights
#define Y_OFF    0
#define YW_SZ    3538944                    // max(y 3,528,000 ; W3'+W4' 3,538,944)
#define W3H_OFF  (Y_OFF)                    // 9*512*512 shorts = 1,179,648 floats
#define W3L_OFF  (W3H_OFF + 1179648)
#define W4H_OFF  (W3L_OFF + 1179648)        // 9*256*512 shorts = 589,824 floats
#define W4L_OFF  (W4H_OFF + 589824)
#define W12_OFF  (Y_OFF + YW_SZ)
#define W1H_OFF  (W12_OFF)                  // 9*128*128 shorts = 73,728 floats
#define W1L_OFF  (W1H_OFF + 73728)
#define W2H_OFF  (W1L_OFF + 73728)
#define W2L_OFF  (W2H_OFF + 294912)
#define BEV_OFF  (W2L_OFF + 294912)
#define BEV_SZ   (NVOX * CFEAT)             // 139,392
#define A0H_OFF  (BEV_OFF + BEV_SZ)         // acts: [1225][CIN] bf16 (hi/lo)
#define A0L_OFF  (A0H_OFF + 78400)
#define A1H_OFF  (A0L_OFF + 78400)
#define A1L_OFF  (A1H_OFF + 78400)
#define A2H_OFF  (A1L_OFF + 78400)          // 1225*512 shorts = 313,600 floats
#define A2L_OFF  (A2H_OFF + 313600)
#define A3H_OFF  (A2L_OFF + 313600)
#define A3L_OFF  (A3H_OFF + 313600)
#define P_OFF    (A3L_OFF + 313600)
#define P_SZ     2230272                    // max slices*1089*COUT (8*1089*256)
#define WS_END   (P_OFF + P_SZ)             // ~32.9 MB
// depthnet weights live at the START of the P region (dead until conv1):
// wdh/wdl each 128*256 shorts = 16384 floats (rows 105..127 zero)
#define WDH_OFF  (P_OFF)
#define WDL_OFF  (P_OFF + 16384)

__device__ __forceinline__ unsigned short f2bf_rn(float f) {
    unsigned u = __builtin_bit_cast(unsigned, f);
    unsigned r = (u + 0x7FFFu + ((u >> 16) & 1u)) >> 16;
    return (unsigned short)r;
}
__device__ __forceinline__ void split_bf(float f, unsigned short& h, unsigned short& l) {
    h = f2bf_rn(f);
    float hf = __builtin_bit_cast(float, (unsigned)h << 16);
    l = f2bf_rn(f - hf);
}

// ---------------- depthnet weight prep: [105][256] -> [128][256] h/l -------
__global__ __launch_bounds__(256) void k_wprep_dn(const float* __restrict__ dnw,
                                                  unsigned short* __restrict__ wdh,
                                                  unsigned short* __restrict__ wdl)
{
    int i = blockIdx.x * 256 + threadIdx.x;
    if (i >= 128 * 256) return;
    int co = i >> 8, ci = i & 255;
    float w = (co < NCH) ? dnw[co * 256 + ci] : 0.f;
    unsigned short h, l; split_bf(w, h, l);
    wdh[i] = h; wdl[i] = l;
}

// ---------------- Stage 1: depthnet via MFMA, barrier-free, no LDS ---------
// grid (88, 6, 2): z picks co-tiles [z*4 .. z*4+3] (tile 7 is zero padding).
// block 256 = 4 waves; wave w owns px range hw0 + w*16 + lp.
// B fragments read directly from global x [ci][hw] (64B segments per
// quarter-wave, L3-resident), split to bf16 h/l in-register. No syncthreads
// -> the K-loop software-pipelines; latency hidden by ILP + 4 blocks/CU.
__global__ __launch_bounds__(256) void k_depthnet_direct(const float* __restrict__ x,
                                                         const unsigned short* __restrict__ wdh,
                                                         const unsigned short* __restrict__ wdl,
                                                         const float* __restrict__ dnb,
                                                         float* __restrict__ y)
{
    const int t  = threadIdx.x;
    const int w  = t >> 6;
    const int l  = t & 63;
    const int lp = l & 15;
    const int q  = l >> 4;
    const int n   = blockIdx.y;
    const int ct0 = blockIdx.z * 4;
    const int px  = blockIdx.x * 64 + w * 16 + lp;
    const bool pok = px < HW;
    const float* xl = x + (size_t)n * INC * HW + (pok ? px : 0);

    f32x4 acc[4];
#pragma unroll
    for (int ct = 0; ct < 4; ++ct) acc[ct] = (f32x4){0.f, 0.f, 0.f, 0.f};

#pragma unroll 2
    for (int ci0 = 0; ci0 < INC; ci0 += 32) {
        // B fragment: 8 fp32 gathers (each a 64B coalesced quarter-wave read)
        float bv[8];
#pragma unroll
        for (int jj = 0; jj < 8; ++jj)
            bv[jj] = xl[(size_t)(ci0 + q * 8 + jj) * HW];
        bf16x8 Bh, Bl;
#pragma unroll
        for (int jj = 0; jj < 8; ++jj) {
            unsigned short h, lo; split_bf(pok ? bv[jj] : 0.f, h, lo);
            Bh[jj] = (short)h; Bl[jj] = (short)lo;
        }
#pragma unroll
        for (int ct = 0; ct < 4; ++ct) {
            const size_t ab = (size_t)((ct0 + ct) * 16 + lp) * 256 + ci0 + q * 8;
            bf16x8 Ah = *(const bf16x8*)&wdh[ab];
            bf16x8 Al = *(const bf16x8*)&wdl[ab];
            acc[ct] = __builtin_amdgcn_mfma_f32_16x16x32_bf16(Ah, Bh, acc[ct], 0, 0, 0);
            acc[ct] = __builtin_amdgcn_mfma_f32_16x16x32_bf16(Ah, Bl, acc[ct], 0, 0, 0);
            acc[ct] = __builtin_amdgcn_mfma_f32_16x16x32_bf16(Al, Bh, acc[ct], 0, 0, 0);
        }
    }
    if (pok) {
#pragma unroll
        for (int ct = 0; ct < 4; ++ct) {
#pragma unroll
            for (int j = 0; j < 4; ++j) {
                int co = (ct0 + ct) * 16 + q * 4 + j;
                if (co < NCH)
                    y[((size_t)n * NCH + co) * HW + px] = acc[ct][j] + dnb[co];
            }
        }
    }
}

// ---------------- Stage 2: softmax over 41 depth channels (in place) -------
__global__ __launch_bounds__(256) void k_softmax(float* __restrict__ y)
{
    int p = blockIdx.x * 256 + threadIdx.x;
    if (p >= NPIX) return;
    int n = p / HW, hw = p - n * HW;
    float* base = y + (size_t)n * NCH * HW + hw;
    float v[DDEP];
    float m = -3.4e38f;
#pragma unroll
    for (int d = 0; d < DDEP; ++d) { v[d] = base[(size_t)d * HW]; m = fmaxf(m, v[d]); }
    float s = 0.f;
#pragma unroll
    for (int d = 0; d < DDEP; ++d) { v[d] = expf(v[d] - m); s += v[d]; }
#pragma unroll
    for (int d = 0; d < DDEP; ++d) base[(size_t)d * HW] = v[d] / s;
}

// ---------------- Stage 3: geometry + lift + splat (atomics) ---------------
__global__ __launch_bounds__(256) void k_splat(const float* __restrict__ y,
                                               const float* __restrict__ rots,
                                               const float* __restrict__ trans,
                                               float* __restrict__ bev)
{
    int idx = blockIdx.x * 256 + threadIdx.x;
    if (idx >= NPIX * DDEP) return;
    int di = idx / NPIX;
    int p  = idx - di * NPIX;
    int n = p / HW, hw = p - n * HW;
    int wi = hw % WW, hi = hw / WW;
    const float su = 1599.0f / 99.0f;
    const float sv = 899.0f / 55.0f;
    float u = __fmul_rn((float)wi, su);
    float v = __fmul_rn((float)hi, sv);
    const float* r = rots + n * 9;
    const float* tr = trans + n * 3;
    float dd  = 4.0f + (float)di;
    float pxv = __fmul_rn(u, dd);
    float pyv = __fmul_rn(v, dd);
    float gx = __fadd_rn(__fadd_rn(__fadd_rn(__fmul_rn(r[0], pxv), __fmul_rn(r[1], pyv)), __fmul_rn(r[2], dd)), tr[0]);
    float gy = __fadd_rn(__fadd_rn(__fadd_rn(__fmul_rn(r[3], pxv), __fmul_rn(r[4], pyv)), __fmul_rn(r[5], dd)), tr[1]);
    float gz = __fadd_rn(__fadd_rn(__fadd_rn(__fmul_rn(r[6], pxv), __fmul_rn(r[7], pyv)), __fmul_rn(r[8], dd)), tr[2]);
    int cx = (int)__fdiv_rn(__fadd_rn(gx, 50.0f), 3.0f);
    int cy = (int)__fdiv_rn(__fadd_rn(gy, 50.0f), 3.0f);
    int cz = (int)__fdiv_rn(__fadd_rn(gz, 5.0f), 3.0f);
    if (cx >= 0 && cx < NXG && cy >= 0 && cy < NYG && cz >= 0 && cz < NZG) {
        const float* dbase = y + (size_t)n * NCH * HW + hw;
        const float* fbase = dbase + (size_t)DDEP * HW;
        float dval = dbase[(size_t)di * HW];
        float* vp = bev + (size_t)((cz * NYG + cy) * NXG + cx) * CFEAT;
#pragma unroll 8
        for (int c = 0; c < CFEAT; ++c) {
            atomicAdd(vp + c, __fmul_rn(dval, fbase[(size_t)c * HW]));
        }
    }
}

// ---------------- conv weight prep: fp32 [CO][CI][3][3] -> h/l [9][CO][CI] -
__global__ __launch_bounds__(256) void k_wprep(const float* __restrict__ wgt,
                                               unsigned short* __restrict__ wh,
                                               unsigned short* __restrict__ wl,
                                               int COUT, int CIN)
{
    int i = blockIdx.x * 256 + threadIdx.x;
    int total = 9 * COUT * CIN;
    if (i >= total) return;
    int ci = i % CIN; int r = i / CIN; int co = r % COUT; int dydx = r / COUT;
    float w = wgt[((size_t)co * CIN + ci) * 9 + dydx];
    unsigned short h, l; split_bf(w, h, l);
    wh[i] = h; wl[i] = l;
}

// ---------------- bev [vox][c] -> act0 transposed [1225][128] bf16 h/l -----
__global__ __launch_bounds__(256) void k_bev2act(const float* __restrict__ bev,
                                                 unsigned short* __restrict__ ah,
                                                 unsigned short* __restrict__ al)
{
    int i = blockIdx.x * 256 + threadIdx.x;
    if (i >= NVOX * CFEAT) return;
    int vx = i >> 6, c = i & 63;
    int cz = vx / NPIXO, rem = vx - cz * NPIXO;
    int yy = rem / NXG, xx = rem - yy * NXG;
    int ch = c * 2 + cz;
    int pos = (yy + 1) * PADW + xx + 1;
    unsigned short h, l; split_bf(bev[i], h, l);
    ah[pos * 128 + ch] = h;
    al[pos * 128 + ch] = l;
}

// ---------------- MFMA 3x3 conv partials (split-bf16, 3-term) --------------
template<int CIN, int COUT, int SL>
__global__ __launch_bounds__(256) void k_conv_mfma(const unsigned short* __restrict__ ah,
                                                   const unsigned short* __restrict__ al,
                                                   const unsigned short* __restrict__ wh,
                                                   const unsigned short* __restrict__ wl,
                                                   float* __restrict__ P)
{
    constexpr int CI_PER = CIN / SL;
    __shared__ unsigned short bs[210 * 64];   // 26.9 KB
    const int t  = threadIdx.x;
    const int w  = t >> 6;
    const int l  = t & 63;
    const int lp = l & 15;
    const int q  = l >> 4;
    const int y0  = blockIdx.x * 4;
    const int cob = blockIdx.y * 64 + w * 16;
    const int sl  = blockIdx.z;
    const int ci_base = sl * CI_PER;

    int  pos0[9];
    bool vld[9];
#pragma unroll
    for (int ct = 0; ct < 9; ++ct) {
        int tp = ct * 16 + lp;
        int r = tp / 33, c = tp - r * 33;
        bool v = (tp < 132) && (y0 + r < 33);
        vld[ct]  = v;
        pos0[ct] = v ? (r * 35 + c) : 0;
    }

    f32x4 acc[9];
#pragma unroll
    for (int ct = 0; ct < 9; ++ct) acc[ct] = (f32x4){0.f, 0.f, 0.f, 0.f};

    for (int chk = 0; chk < CI_PER; chk += 32) {
        const int ci0 = ci_base + chk;
        __syncthreads();
        for (int i = t; i < 210 * 8; i += 256) {
            int pos = i >> 3, s = i & 7;
            int gpos = y0 * 35 + pos;
            const unsigned short* src = (s < 4) ? ah : al;
            int sp = s ^ (pos & 7);
            uint4 val = make_uint4(0u, 0u, 0u, 0u);
            if (gpos < PADHW)
                val = *(const uint4*)&src[(size_t)gpos * CIN + ci0 + (s & 3) * 8];
            *(uint4*)&bs[pos * 64 + sp * 8] = val;
        }
        __syncthreads();

#pragma unroll 3
        for (int dydx = 0; dydx < 9; ++dydx) {
            int dy = dydx / 3, dx = dydx - dy * 3;
            int off = dy * 35 + dx;
            const size_t abase = ((size_t)dydx * COUT + cob + lp) * CIN + ci0 + q * 8;
            bf16x8 Ah = *(const bf16x8*)&wh[abase];
            bf16x8 Al = *(const bf16x8*)&wl[abase];
#pragma unroll
            for (int ct = 0; ct < 9; ++ct) {
                int pos = pos0[ct] + off;
                int sph = q ^ (pos & 7);
                bf16x8 Bh = *(const bf16x8*)&bs[pos * 64 + sph * 8];
                bf16x8 Bl = *(const bf16x8*)&bs[pos * 64 + (sph ^ 4) * 8];
                acc[ct] = __builtin_amdgcn_mfma_f32_16x16x32_bf16(Ah, Bh, acc[ct], 0, 0, 0);
                acc[ct] = __builtin_amdgcn_mfma_f32_16x16x32_bf16(Ah, Bl, acc[ct], 0, 0, 0);
                acc[ct] = __builtin_amdgcn_mfma_f32_16x16x32_bf16(Al, Bh, acc[ct], 0, 0, 0);
            }
        }
    }

#pragma unroll
    for (int ct = 0; ct < 9; ++ct) {
        if (!vld[ct]) continue;
        int gp = y0 * 33 + ct * 16 + lp;
        float* dst = P + ((size_t)sl * NPIXO + gp) * COUT + cob + q * 4;
        *(f32x4*)dst = acc[ct];
    }
}

// ---------------- reduce slices + BN + ReLU -> next act (or final out) -----
template<int SL>
__global__ __launch_bounds__(256) void k_finish(const float* __restrict__ P,
                                                const float* __restrict__ bns,
                                                const float* __restrict__ bnb,
                                                const float* __restrict__ bnm,
                                                const float* __restrict__ bnv,
                                                unsigned short* __restrict__ oh,
                                                unsigned short* __restrict__ ol,
                                                float* __restrict__ outf,
                                                int COUT)
{
    int i = blockIdx.x * 256 + threadIdx.x;
    if (i >= COUT * NPIXO) return;
    int co = i % COUT, p = i / COUT;
    float s = 0.f;
#pragma unroll
    for (int sl = 0; sl < SL; ++sl)
        s += P[((size_t)sl * NPIXO + p) * COUT + co];
    float sc = bns[co] / sqrtf(bnv[co] + 1e-5f);
    float bi = bnb[co] - bnm[co] * sc;
    float rv = fmaxf(fmaf(s, sc, bi), 0.f);
    if (outf) {
        outf[(size_t)co * NPIXO + p] = rv;
    } else {
        int yy = p / NXG, xx = p - yy * NXG;
        int pos = (yy + 1) * PADW + xx + 1;
        unsigned short h, lo; split_bf(rv, h, lo);
        oh[(size_t)pos * COUT + co] = h;
        ol[(size_t)pos * COUT + co] = lo;
    }
}

extern "C" void kernel_launch(void* const* d_in, const int* in_sizes, int n_in,
                              void* d_out, int out_size, void* d_ws, size_t ws_size,
                              hipStream_t stream)
{
    const float* x     = (const float*)d_in[0];
    const float* rots  = (const float*)d_in[1];
    const float* trans = (const float*)d_in[2];
    const float* dnw   = (const float*)d_in[3];
    const float* dnb   = (const float*)d_in[4];
    const float* bw1   = (const float*)d_in[5];
    const float* bn1s  = (const float*)d_in[6];
    const float* bn1b  = (const float*)d_in[7];
    const float* bn1m  = (const float*)d_in[8];
    const float* bn1v  = (const float*)d_in[9];
    const float* bw2   = (const float*)d_in[10];
    const float* bn2s  = (const float*)d_in[11];
    const float* bn2b  = (const float*)d_in[12];
    const float* bn2m  = (const float*)d_in[13];
    const float* bn2v  = (const float*)d_in[14];
    const float* bw3   = (const float*)d_in[15];
    const float* bn3s  = (const float*)d_in[16];
    const float* bn3b  = (const float*)d_in[17];
    const float* bn3m  = (const float*)d_in[18];
    const float* bn3v  = (const float*)d_in[19];
    const float* bw4   = (const float*)d_in[20];
    const float* bn4s  = (const float*)d_in[21];
    const float* bn4b  = (const float*)d_in[22];
    const float* bn4m  = (const float*)d_in[23];
    const float* bn4v  = (const float*)d_in[24];

    float* ws  = (float*)d_ws;
    float* y   = ws + Y_OFF;
    float* bev = ws + BEV_OFF;
    float* P   = ws + P_OFF;
    unsigned short* w1h = (unsigned short*)(ws + W1H_OFF);
    unsigned short* w1l = (unsigned short*)(ws + W1L_OFF);
    unsigned short* w2h = (unsigned short*)(ws + W2H_OFF);
    unsigned short* w2l = (unsigned short*)(ws + W2L_OFF);
    unsigned short* w3h = (unsigned short*)(ws + W3H_OFF);
    unsigned short* w3l = (unsigned short*)(ws + W3L_OFF);
    unsigned short* w4h = (unsigned short*)(ws + W4H_OFF);
    unsigned short* w4l = (unsigned short*)(ws + W4L_OFF);
    unsigned short* a0h = (unsigned short*)(ws + A0H_OFF);
    unsigned short* a0l = (unsigned short*)(ws + A0L_OFF);
    unsigned short* a1h = (unsigned short*)(ws + A1H_OFF);
    unsigned short* a1l = (unsigned short*)(ws + A1L_OFF);
    unsigned short* a2h = (unsigned short*)(ws + A2H_OFF);
    unsigned short* a2l = (unsigned short*)(ws + A2L_OFF);
    unsigned short* a3h = (unsigned short*)(ws + A3H_OFF);
    unsigned short* a3l = (unsigned short*)(ws + A3L_OFF);
    unsigned short* wdh = (unsigned short*)(ws + WDH_OFF);
    unsigned short* wdl = (unsigned short*)(ws + WDL_OFF);
    float* out = (float*)d_out;

    // zero bev accumulator + act buffers (their padded borders must be 0)
    hipMemsetAsync(bev, 0, (size_t)(P_OFF - BEV_OFF) * sizeof(float), stream);

    // depthnet: weight prep (lives in P region, dead until conv1) + MFMA GEMM
    k_wprep_dn<<<128, 256, 0, stream>>>(dnw, wdh, wdl);
    k_depthnet_direct<<<dim3(88, 6, 2), 256, 0, stream>>>(x, wdh, wdl, dnb, y);
    k_softmax<<<132, 256, 0, stream>>>(y);
    k_splat<<<(NPIX * DDEP + 255) / 256, 256, 0, stream>>>(y, rots, trans, bev);

    // conv weight prep (w3/w4 reuse the y region -> must be after splat)
    k_wprep<<<(9 * 128 * 128 + 255) / 256, 256, 0, stream>>>(bw1, w1h, w1l, 128, 128);
    k_wprep<<<(9 * 512 * 128 + 255) / 256, 256, 0, stream>>>(bw2, w2h, w2l, 512, 128);
    k_wprep<<<(9 * 512 * 512 + 255) / 256, 256, 0, stream>>>(bw3, w3h, w3l, 512, 512);
    k_wprep<<<(9 * 256 * 512 + 255) / 256, 256, 0, stream>>>(bw4, w4h, w4l, 256, 512);

    k_bev2act<<<(NVOX * CFEAT + 255) / 256, 256, 0, stream>>>(bev, a0h, a0l);

    // conv1: 128 -> 128
    k_conv_mfma<128, 128, 4><<<dim3(9, 2, 4), 256, 0, stream>>>(a0h, a0l, w1h, w1l, P);
    k_finish<4><<<(128 * NPIXO + 255) / 256, 256, 0, stream>>>(P, bn1s, bn1b, bn1m, bn1v, a1h, a1l, nullptr, 128);
    // conv2: 128 -> 512
    k_conv_mfma<128, 512, 4><<<dim3(9, 8, 4), 256, 0, stream>>>(a1h, a1l, w2h, w2l, P);
    k_finish<4><<<(512 * NPIXO + 255) / 256, 256, 0, stream>>>(P, bn2s, bn2b, bn2m, bn2v, a2h, a2l, nullptr, 512);
    // conv3: 512 -> 512
    k_conv_mfma<512, 512, 4><<<dim3(9, 8, 4), 256, 0, stream>>>(a2h, a2l, w3h, w3l, P);
    k_finish<4><<<(512 * NPIXO + 255) / 256, 256, 0, stream>>>(P, bn3s, bn3b, bn3m, bn3v, a3h, a3l, nullptr, 512);
    // conv4: 512 -> 256 (final, fp32 out [256][33][33])
    k_conv_mfma<512, 256, 8><<<dim3(9, 4, 8), 256, 0, stream>>>(a3h, a3l, w4h, w4l, P);
    k_finish<8><<<(256 * NPIXO + 255) / 256, 256, 0, stream>>>(P, bn4s, bn4b, bn4m, bn4v, nullptr, nullptr, out, 256);
}

// Round 6
// 168.717 us; speedup vs baseline: 8.5485x; 1.1940x over previous
//
#include <hip/hip_runtime.h>
#include <math.h>

#define NCAM  6
#define INC   256
#define HH    56
#define WW    100
#define HW    5600
#define NPIX  33600
#define DDEP  41
#define CFEAT 64
#define NCH   105          // 41 depth + 64 feat
#define NXG   33
#define NYG   33
#define NZG   2
#define NVOX  2178         // 2*33*33
#define PADW  35
#define PADHW 1225         // 35*35
#define NPIXO 1089         // 33*33

typedef short bf16x8 __attribute__((ext_vector_type(8)));
typedef float f32x4  __attribute__((ext_vector_type(4)));

// ---- workspace layout (floats) ----
// Y region: depthnet output y until splat; then reused for conv3/conv4 weights
#define Y_OFF    0
#define YW_SZ    3538944                    // max(y 3,528,000 ; W3'+W4' 3,538,944)
#define W3H_OFF  (Y_OFF)                    // 9*512*512 shorts = 1,179,648 floats
#define W3L_OFF  (W3H_OFF + 1179648)
#define W4H_OFF  (W3L_OFF + 1179648)        // 9*256*512 shorts = 589,824 floats
#define W4L_OFF  (W4H_OFF + 589824)
#define W12_OFF  (Y_OFF + YW_SZ)
#define W1H_OFF  (W12_OFF)                  // 9*128*128 shorts = 73,728 floats
#define W1L_OFF  (W1H_OFF + 73728)
#define W2H_OFF  (W1L_OFF + 73728)
#define W2L_OFF  (W2H_OFF + 294912)
#define BEV_OFF  (W2L_OFF + 294912)
#define BEV_SZ   (NVOX * CFEAT)             // 139,392
#define A0H_OFF  (BEV_OFF + BEV_SZ)         // acts: [1225][CIN] bf16 (hi/lo)
#define A0L_OFF  (A0H_OFF + 78400)
#define A1H_OFF  (A0L_OFF + 78400)
#define A1L_OFF  (A1H_OFF + 78400)
#define A2H_OFF  (A1L_OFF + 78400)          // 1225*512 shorts = 313,600 floats
#define A2L_OFF  (A2H_OFF + 313600)
#define A3H_OFF  (A2L_OFF + 313600)
#define A3L_OFF  (A3H_OFF + 313600)
#define P_OFF    (A3L_OFF + 313600)
#define P_SZ     2230272                    // max slices*1089*COUT (8*1089*256)
#define WS_END   (P_OFF + P_SZ)             // ~32.9 MB
// depthnet weights live at the START of the P region (dead until conv1):
// wdh/wdl each 128*256 shorts = 16384 floats (rows 105..127 zero)
#define WDH_OFF  (P_OFF)
#define WDL_OFF  (P_OFF + 16384)

__device__ __forceinline__ unsigned short f2bf_rn(float f) {
    unsigned u = __builtin_bit_cast(unsigned, f);
    unsigned r = (u + 0x7FFFu + ((u >> 16) & 1u)) >> 16;
    return (unsigned short)r;
}
__device__ __forceinline__ void split_bf(float f, unsigned short& h, unsigned short& l) {
    h = f2bf_rn(f);
    float hf = __builtin_bit_cast(float, (unsigned)h << 16);
    l = f2bf_rn(f - hf);
}

// ---------------- depthnet weight prep -> fragment layout ------------------
// [ct 0..7][chk 0..7][lane 0..63][jj 0..7]; co = ct*16+(lane&15),
// ci = chk*32+(lane>>4)*8+jj. A wave's fragment = contiguous 1KB.
__global__ __launch_bounds__(256) void k_wprep_dn(const float* __restrict__ dnw,
                                                  unsigned short* __restrict__ wdh,
                                                  unsigned short* __restrict__ wdl)
{
    int i = blockIdx.x * 256 + threadIdx.x;
    if (i >= 128 * 256) return;
    int jj = i & 7, lane = (i >> 3) & 63, chk = (i >> 9) & 7, ct = i >> 12;
    int co = ct * 16 + (lane & 15);
    int ci = chk * 32 + (lane >> 4) * 8 + jj;
    float w = (co < NCH) ? dnw[co * 256 + ci] : 0.f;
    unsigned short h, l; split_bf(w, h, l);
    wdh[i] = h; wdl[i] = l;
}

// ---------------- Stage 1: depthnet via MFMA, barrier-free, no LDS ---------
__global__ __launch_bounds__(256) void k_depthnet_direct(const float* __restrict__ x,
                                                         const unsigned short* __restrict__ wdh,
                                                         const unsigned short* __restrict__ wdl,
                                                         const float* __restrict__ dnb,
                                                         float* __restrict__ y)
{
    const int t  = threadIdx.x;
    const int w  = t >> 6;
    const int l  = t & 63;
    const int lp = l & 15;
    const int q  = l >> 4;
    const int n   = blockIdx.y;
    const int ct0 = blockIdx.z * 4;
    const int px  = blockIdx.x * 64 + w * 16 + lp;
    const bool pok = px < HW;
    const float* xl = x + (size_t)n * INC * HW + (pok ? px : 0);

    f32x4 acc[4];
#pragma unroll
    for (int ct = 0; ct < 4; ++ct) acc[ct] = (f32x4){0.f, 0.f, 0.f, 0.f};

#pragma unroll 2
    for (int ci0 = 0; ci0 < INC; ci0 += 32) {
        float bv[8];
#pragma unroll
        for (int jj = 0; jj < 8; ++jj)
            bv[jj] = xl[(size_t)(ci0 + q * 8 + jj) * HW];
        bf16x8 Bh, Bl;
#pragma unroll
        for (int jj = 0; jj < 8; ++jj) {
            unsigned short h, lo; split_bf(pok ? bv[jj] : 0.f, h, lo);
            Bh[jj] = (short)h; Bl[jj] = (short)lo;
        }
#pragma unroll
        for (int ct = 0; ct < 4; ++ct) {
            const size_t ab = (size_t)(((ct0 + ct) * 8 + (ci0 >> 5)) * 64 + l) * 8;
            bf16x8 Ah = *(const bf16x8*)&wdh[ab];
            bf16x8 Al = *(const bf16x8*)&wdl[ab];
            acc[ct] = __builtin_amdgcn_mfma_f32_16x16x32_bf16(Ah, Bh, acc[ct], 0, 0, 0);
            acc[ct] = __builtin_amdgcn_mfma_f32_16x16x32_bf16(Ah, Bl, acc[ct], 0, 0, 0);
            acc[ct] = __builtin_amdgcn_mfma_f32_16x16x32_bf16(Al, Bh, acc[ct], 0, 0, 0);
        }
    }
    if (pok) {
#pragma unroll
        for (int ct = 0; ct < 4; ++ct) {
#pragma unroll
            for (int j = 0; j < 4; ++j) {
                int co = (ct0 + ct) * 16 + q * 4 + j;
                if (co < NCH)
                    y[((size_t)n * NCH + co) * HW + px] = acc[ct][j] + dnb[co];
            }
        }
    }
}

// ---------------- Stage 2: softmax over 41 depth channels (in place) -------
__global__ __launch_bounds__(256) void k_softmax(float* __restrict__ y)
{
    int p = blockIdx.x * 256 + threadIdx.x;
    if (p >= NPIX) return;
    int n = p / HW, hw = p - n * HW;
    float* base = y + (size_t)n * NCH * HW + hw;
    float v[DDEP];
    float m = -3.4e38f;
#pragma unroll
    for (int d = 0; d < DDEP; ++d) { v[d] = base[(size_t)d * HW]; m = fmaxf(m, v[d]); }
    float s = 0.f;
#pragma unroll
    for (int d = 0; d < DDEP; ++d) { v[d] = expf(v[d] - m); s += v[d]; }
#pragma unroll
    for (int d = 0; d < DDEP; ++d) base[(size_t)d * HW] = v[d] / s;
}

// ---------------- Stage 3: geometry + lift + splat (atomics) ---------------
__global__ __launch_bounds__(256) void k_splat(const float* __restrict__ y,
                                               const float* __restrict__ rots,
                                               const float* __restrict__ trans,
                                               float* __restrict__ bev)
{
    int idx = blockIdx.x * 256 + threadIdx.x;
    if (idx >= NPIX * DDEP) return;
    int di = idx / NPIX;
    int p  = idx - di * NPIX;
    int n = p / HW, hw = p - n * HW;
    int wi = hw % WW, hi = hw / WW;
    const float su = 1599.0f / 99.0f;
    const float sv = 899.0f / 55.0f;
    float u = __fmul_rn((float)wi, su);
    float v = __fmul_rn((float)hi, sv);
    const float* r = rots + n * 9;
    const float* tr = trans + n * 3;
    float dd  = 4.0f + (float)di;
    float pxv = __fmul_rn(u, dd);
    float pyv = __fmul_rn(v, dd);
    float gx = __fadd_rn(__fadd_rn(__fadd_rn(__fmul_rn(r[0], pxv), __fmul_rn(r[1], pyv)), __fmul_rn(r[2], dd)), tr[0]);
    float gy = __fadd_rn(__fadd_rn(__fadd_rn(__fmul_rn(r[3], pxv), __fmul_rn(r[4], pyv)), __fmul_rn(r[5], dd)), tr[1]);
    float gz = __fadd_rn(__fadd_rn(__fadd_rn(__fmul_rn(r[6], pxv), __fmul_rn(r[7], pyv)), __fmul_rn(r[8], dd)), tr[2]);
    int cx = (int)__fdiv_rn(__fadd_rn(gx, 50.0f), 3.0f);
    int cy = (int)__fdiv_rn(__fadd_rn(gy, 50.0f), 3.0f);
    int cz = (int)__fdiv_rn(__fadd_rn(gz, 5.0f), 3.0f);
    if (cx >= 0 && cx < NXG && cy >= 0 && cy < NYG && cz >= 0 && cz < NZG) {
        const float* dbase = y + (size_t)n * NCH * HW + hw;
        const float* fbase = dbase + (size_t)DDEP * HW;
        float dval = dbase[(size_t)di * HW];
        float* vp = bev + (size_t)((cz * NYG + cy) * NXG + cx) * CFEAT;
#pragma unroll 8
        for (int c = 0; c < CFEAT; ++c) {
            atomicAdd(vp + c, __fmul_rn(dval, fbase[(size_t)c * HW]));
        }
    }
}

// ---------------- conv weight prep -> fragment layout ----------------------
// [dydx][cog][chk][lane][jj]: co = cog*16+(lane&15), ci = chk*32+(lane>>4)*8+jj
__global__ __launch_bounds__(256) void k_wprep(const float* __restrict__ wgt,
                                               unsigned short* __restrict__ wh,
                                               unsigned short* __restrict__ wl,
                                               int COUT, int CIN)
{
    int i = blockIdx.x * 256 + threadIdx.x;
    int total = 9 * COUT * CIN;
    if (i >= total) return;
    int jj = i & 7, lane = (i >> 3) & 63;
    int r  = i >> 9;
    int nchk = CIN >> 5;
    int chk = r % nchk; r /= nchk;
    int ncog = COUT >> 4;
    int cog = r % ncog; int dydx = r / ncog;
    int co = cog * 16 + (lane & 15);
    int ci = chk * 32 + (lane >> 4) * 8 + jj;
    float w = wgt[((size_t)co * CIN + ci) * 9 + dydx];
    unsigned short h, l; split_bf(w, h, l);
    wh[i] = h; wl[i] = l;
}

// ---------------- bev [vox][c] -> act0 transposed [1225][128] bf16 h/l -----
__global__ __launch_bounds__(256) void k_bev2act(const float* __restrict__ bev,
                                                 unsigned short* __restrict__ ah,
                                                 unsigned short* __restrict__ al)
{
    int i = blockIdx.x * 256 + threadIdx.x;
    if (i >= NVOX * CFEAT) return;
    int vx = i >> 6, c = i & 63;
    int cz = vx / NPIXO, rem = vx - cz * NPIXO;
    int yy = rem / NXG, xx = rem - yy * NXG;
    int ch = c * 2 + cz;
    int pos = (yy + 1) * PADW + xx + 1;
    unsigned short h, l; split_bf(bev[i], h, l);
    ah[pos * 128 + ch] = h;
    al[pos * 128 + ch] = l;
}

// ---------------- MFMA 3x3 conv partials (split-bf16, 3-term) --------------
// 1D grid, XCD-grouped: xcd = bid&7 owns all 9 y-tiles of G/8 (cob,sl)
// groups -> weight slice L2-resident on exactly one XCD.
template<int CIN, int COUT, int SL>
__global__ __launch_bounds__(256) void k_conv_mfma(const unsigned short* __restrict__ ah,
                                                   const unsigned short* __restrict__ al,
                                                   const unsigned short* __restrict__ wh,
                                                   const unsigned short* __restrict__ wl,
                                                   float* __restrict__ P)
{
    constexpr int CI_PER = CIN / SL;
    constexpr int NCOB = COUT / 64;
    constexpr int G    = NCOB * SL;      // (cob,sl) groups; G%8==0 for all convs
    constexpr int GX   = G / 8;
    __shared__ unsigned short bs[210 * 64];   // 26.9 KB
    const int t  = threadIdx.x;
    const int w  = t >> 6;
    const int l  = t & 63;
    const int lp = l & 15;
    const int q  = l >> 4;

    const int bid   = blockIdx.x;
    const int xcd   = bid & 7;
    const int slot  = bid >> 3;
    const int ytile = slot % 9;
    const int gon   = slot / 9;
    const int group = xcd * GX + gon;
    const int cobi  = group % NCOB;
    const int sl    = group / NCOB;

    const int y0  = ytile * 4;
    const int cob = cobi * 64 + w * 16;
    const int ci_base = sl * CI_PER;

    int  pos0[9];
    bool vld[9];
#pragma unroll
    for (int ct = 0; ct < 9; ++ct) {
        int tp = ct * 16 + lp;
        int r = tp / 33, c = tp - r * 33;
        bool v = (tp < 132) && (y0 + r < 33);
        vld[ct]  = v;
        pos0[ct] = v ? (r * 35 + c) : 0;
    }

    f32x4 acc[9];
#pragma unroll
    for (int ct = 0; ct < 9; ++ct) acc[ct] = (f32x4){0.f, 0.f, 0.f, 0.f};

    for (int chk = 0; chk < CI_PER; chk += 32) {
        const int ci0 = ci_base + chk;
        __syncthreads();
        for (int i = t; i < 210 * 8; i += 256) {
            int pos = i >> 3, s = i & 7;
            int gpos = y0 * 35 + pos;
            const unsigned short* src = (s < 4) ? ah : al;
            int sp = s ^ (pos & 7);
            uint4 val = make_uint4(0u, 0u, 0u, 0u);
            if (gpos < PADHW)
                val = *(const uint4*)&src[(size_t)gpos * CIN + ci0 + (s & 3) * 8];
            *(uint4*)&bs[pos * 64 + sp * 8] = val;
        }
        __syncthreads();

#pragma unroll 3
        for (int dydx = 0; dydx < 9; ++dydx) {
            int dy = dydx / 3, dx = dydx - dy * 3;
            int off = dy * 35 + dx;
            // fragment-contiguous A: one 1KB coalesced read per wave
            const size_t abase = (size_t)(((dydx * (COUT >> 4) + (cob >> 4)) * (CIN >> 5)
                                           + (ci0 >> 5)) * 64 + l) * 8;
            bf16x8 Ah = *(const bf16x8*)&wh[abase];
            bf16x8 Al = *(const bf16x8*)&wl[abase];
#pragma unroll
            for (int ct = 0; ct < 9; ++ct) {
                int pos = pos0[ct] + off;
                int sph = q ^ (pos & 7);
                bf16x8 Bh = *(const bf16x8*)&bs[pos * 64 + sph * 8];
                bf16x8 Bl = *(const bf16x8*)&bs[pos * 64 + (sph ^ 4) * 8];
                acc[ct] = __builtin_amdgcn_mfma_f32_16x16x32_bf16(Ah, Bh, acc[ct], 0, 0, 0);
                acc[ct] = __builtin_amdgcn_mfma_f32_16x16x32_bf16(Ah, Bl, acc[ct], 0, 0, 0);
                acc[ct] = __builtin_amdgcn_mfma_f32_16x16x32_bf16(Al, Bh, acc[ct], 0, 0, 0);
            }
        }
    }

#pragma unroll
    for (int ct = 0; ct < 9; ++ct) {
        if (!vld[ct]) continue;
        int gp = y0 * 33 + ct * 16 + lp;
        float* dst = P + ((size_t)sl * NPIXO + gp) * COUT + cob + q * 4;
        *(f32x4*)dst = acc[ct];
    }
}

// ---------------- reduce slices + BN + ReLU -> next act (or final out) -----
template<int SL>
__global__ __launch_bounds__(256) void k_finish(const float* __restrict__ P,
                                                const float* __restrict__ bns,
                                                const float* __restrict__ bnb,
                                                const float* __restrict__ bnm,
                                                const float* __restrict__ bnv,
                                                unsigned short* __restrict__ oh,
                                                unsigned short* __restrict__ ol,
                                                float* __restrict__ outf,
                                                int COUT)
{
    int i = blockIdx.x * 256 + threadIdx.x;
    if (i >= COUT * NPIXO) return;
    int co = i % COUT, p = i / COUT;
    float s = 0.f;
#pragma unroll
    for (int sl = 0; sl < SL; ++sl)
        s += P[((size_t)sl * NPIXO + p) * COUT + co];
    float sc = bns[co] / sqrtf(bnv[co] + 1e-5f);
    float bi = bnb[co] - bnm[co] * sc;
    float rv = fmaxf(fmaf(s, sc, bi), 0.f);
    if (outf) {
        outf[(size_t)co * NPIXO + p] = rv;
    } else {
        int yy = p / NXG, xx = p - yy * NXG;
        int pos = (yy + 1) * PADW + xx + 1;
        unsigned short h, lo; split_bf(rv, h, lo);
        oh[(size_t)pos * COUT + co] = h;
        ol[(size_t)pos * COUT + co] = lo;
    }
}

extern "C" void kernel_launch(void* const* d_in, const int* in_sizes, int n_in,
                              void* d_out, int out_size, void* d_ws, size_t ws_size,
                              hipStream_t stream)
{
    const float* x     = (const float*)d_in[0];
    const float* rots  = (const float*)d_in[1];
    const float* trans = (const float*)d_in[2];
    const float* dnw   = (const float*)d_in[3];
    const float* dnb   = (const float*)d_in[4];
    const float* bw1   = (const float*)d_in[5];
    const float* bn1s  = (const float*)d_in[6];
    const float* bn1b  = (const float*)d_in[7];
    const float* bn1m  = (const float*)d_in[8];
    const float* bn1v  = (const float*)d_in[9];
    const float* bw2   = (const float*)d_in[10];
    const float* bn2s  = (const float*)d_in[11];
    const float* bn2b  = (const float*)d_in[12];
    const float* bn2m  = (const float*)d_in[13];
    const float* bn2v  = (const float*)d_in[14];
    const float* bw3   = (const float*)d_in[15];
    const float* bn3s  = (const float*)d_in[16];
    const float* bn3b  = (const float*)d_in[17];
    const float* bn3m  = (const float*)d_in[18];
    const float* bn3v  = (const float*)d_in[19];
    const float* bw4   = (const float*)d_in[20];
    const float* bn4s  = (const float*)d_in[21];
    const float* bn4b  = (const float*)d_in[22];
    const float* bn4m  = (const float*)d_in[23];
    const float* bn4v  = (const float*)d_in[24];

    float* ws  = (float*)d_ws;
    float* y   = ws + Y_OFF;
    float* bev = ws + BEV_OFF;
    float* P   = ws + P_OFF;
    unsigned short* w1h = (unsigned short*)(ws + W1H_OFF);
    unsigned short* w1l = (unsigned short*)(ws + W1L_OFF);
    unsigned short* w2h = (unsigned short*)(ws + W2H_OFF);
    unsigned short* w2l = (unsigned short*)(ws + W2L_OFF);
    unsigned short* w3h = (unsigned short*)(ws + W3H_OFF);
    unsigned short* w3l = (unsigned short*)(ws + W3L_OFF);
    unsigned short* w4h = (unsigned short*)(ws + W4H_OFF);
    unsigned short* w4l = (unsigned short*)(ws + W4L_OFF);
    unsigned short* a0h = (unsigned short*)(ws + A0H_OFF);
    unsigned short* a0l = (unsigned short*)(ws + A0L_OFF);
    unsigned short* a1h = (unsigned short*)(ws + A1H_OFF);
    unsigned short* a1l = (unsigned short*)(ws + A1L_OFF);
    unsigned short* a2h = (unsigned short*)(ws + A2H_OFF);
    unsigned short* a2l = (unsigned short*)(ws + A2L_OFF);
    unsigned short* a3h = (unsigned short*)(ws + A3H_OFF);
    unsigned short* a3l = (unsigned short*)(ws + A3L_OFF);
    unsigned short* wdh = (unsigned short*)(ws + WDH_OFF);
    unsigned short* wdl = (unsigned short*)(ws + WDL_OFF);
    float* out = (float*)d_out;

    // zero bev accumulator + act buffers (their padded borders must be 0)
    hipMemsetAsync(bev, 0, (size_t)(P_OFF - BEV_OFF) * sizeof(float), stream);

    // depthnet: weight prep (lives in P region, dead until conv1) + MFMA GEMM
    k_wprep_dn<<<128, 256, 0, stream>>>(dnw, wdh, wdl);
    k_depthnet_direct<<<dim3(88, 6, 2), 256, 0, stream>>>(x, wdh, wdl, dnb, y);
    k_softmax<<<132, 256, 0, stream>>>(y);
    k_splat<<<(NPIX * DDEP + 255) / 256, 256, 0, stream>>>(y, rots, trans, bev);

    // conv weight prep (w3/w4 reuse the y region -> must be after splat)
    k_wprep<<<(9 * 128 * 128 + 255) / 256, 256, 0, stream>>>(bw1, w1h, w1l, 128, 128);
    k_wprep<<<(9 * 512 * 128 + 255) / 256, 256, 0, stream>>>(bw2, w2h, w2l, 512, 128);
    k_wprep<<<(9 * 512 * 512 + 255) / 256, 256, 0, stream>>>(bw3, w3h, w3l, 512, 512);
    k_wprep<<<(9 * 256 * 512 + 255) / 256, 256, 0, stream>>>(bw4, w4h, w4l, 256, 512);

    k_bev2act<<<(NVOX * CFEAT + 255) / 256, 256, 0, stream>>>(bev, a0h, a0l);

    // conv1: 128 -> 128   (72 blocks: 8 groups x 9 y-tiles)
    k_conv_mfma<128, 128, 4><<<72, 256, 0, stream>>>(a0h, a0l, w1h, w1l, P);
    k_finish<4><<<(128 * NPIXO + 255) / 256, 256, 0, stream>>>(P, bn1s, bn1b, bn1m, bn1v, a1h, a1l, nullptr, 128);
    // conv2: 128 -> 512   (288 blocks: 32 groups x 9 y-tiles)
    k_conv_mfma<128, 512, 4><<<288, 256, 0, stream>>>(a1h, a1l, w2h, w2l, P);
    k_finish<4><<<(512 * NPIXO + 255) / 256, 256, 0, stream>>>(P, bn2s, bn2b, bn2m, bn2v, a2h, a2l, nullptr, 512);
    // conv3: 512 -> 512
    k_conv_mfma<512, 512, 4><<<288, 256, 0, stream>>>(a2h, a2l, w3h, w3l, P);
    k_finish<4><<<(512 * NPIXO + 255) / 256, 256, 0, stream>>>(P, bn3s, bn3b, bn3m, bn3v, a3h, a3l, nullptr, 512);
    // conv4: 512 -> 256 (final, fp32 out [256][33][33])
    k_conv_mfma<512, 256, 8><<<288, 256, 0, stream>>>(a3h, a3l, w4h, w4l, P);
    k_finish<8><<<(256 * NPIXO + 255) / 256, 256, 0, stream>>>(P, bn4s, bn4b, bn4m, bn4v, nullptr, nullptr, out, 256);
}

// Round 7
// 144.662 us; speedup vs baseline: 9.9699x; 1.1663x over previous
//
#include <hip/hip_runtime.h>
#include <math.h>

#define NCAM  6
#define INC   256
#define HH    56
#define WW    100
#define HW    5600
#define NPIX  33600
#define DDEP  41
#define CFEAT 64
#define NCH   105          // 41 depth + 64 feat
#define NXG   33
#define NYG   33
#define NZG   2
#define NVOX  2178         // 2*33*33
#define PADW  35
#define PADHW 1225         // 35*35
#define NPIXO 1089         // 33*33

typedef short bf16x8 __attribute__((ext_vector_type(8)));
typedef float f32x4  __attribute__((ext_vector_type(4)));

// ---- workspace layout (floats); ws_size ~268 MB (harness poison showed it)
#define Y_OFF    0
#define YW_SZ    3538944                    // max(y 3,528,000 ; W3'+W4' 3,538,944)
#define W3H_OFF  (Y_OFF)                    // 9*512*512 shorts = 1,179,648 floats
#define W3L_OFF  (W3H_OFF + 1179648)
#define W4H_OFF  (W3L_OFF + 1179648)        // 9*256*512 shorts = 589,824 floats
#define W4L_OFF  (W4H_OFF + 589824)
#define W12_OFF  (Y_OFF + YW_SZ)
#define W1H_OFF  (W12_OFF)                  // 9*128*128 shorts = 73,728 floats
#define W1L_OFF  (W1H_OFF + 73728)
#define W2H_OFF  (W1L_OFF + 73728)
#define W2L_OFF  (W2H_OFF + 294912)
#define BEV_OFF  (W2L_OFF + 294912)
#define BEV_SZ   (NVOX * CFEAT)             // 139,392
#define A0H_OFF  (BEV_OFF + BEV_SZ)         // acts: [1225][CIN] bf16 (hi/lo)
#define A0L_OFF  (A0H_OFF + 78400)
#define A1H_OFF  (A0L_OFF + 78400)
#define A1L_OFF  (A1H_OFF + 78400)
#define A2H_OFF  (A1L_OFF + 78400)          // 1225*512 shorts = 313,600 floats
#define A2L_OFF  (A2H_OFF + 313600)
#define A3H_OFF  (A2L_OFF + 313600)
#define A3L_OFF  (A3H_OFF + 313600)
#define P_OFF    (A3L_OFF + 313600)
#define P_SZ     4460544                    // max slices*1089*COUT (8*1089*512)
#define WS_END   (P_OFF + P_SZ)             // ~41.8 MB  (ws is ~268 MB)
// depthnet weights live at the START of the P region (dead until conv1):
#define WDH_OFF  (P_OFF)
#define WDL_OFF  (P_OFF + 16384)

__device__ __forceinline__ unsigned short f2bf_rn(float f) {
    unsigned u = __builtin_bit_cast(unsigned, f);
    unsigned r = (u + 0x7FFFu + ((u >> 16) & 1u)) >> 16;
    return (unsigned short)r;
}
__device__ __forceinline__ void split_bf(float f, unsigned short& h, unsigned short& l) {
    h = f2bf_rn(f);
    float hf = __builtin_bit_cast(float, (unsigned)h << 16);
    l = f2bf_rn(f - hf);
}

// ---------------- depthnet weight prep -> fragment layout ------------------
__global__ __launch_bounds__(256) void k_wprep_dn(const float* __restrict__ dnw,
                                                  unsigned short* __restrict__ wdh,
                                                  unsigned short* __restrict__ wdl)
{
    int i = blockIdx.x * 256 + threadIdx.x;
    if (i >= 128 * 256) return;
    int jj = i & 7, lane = (i >> 3) & 63, chk = (i >> 9) & 7, ct = i >> 12;
    int co = ct * 16 + (lane & 15);
    int ci = chk * 32 + (lane >> 4) * 8 + jj;
    float w = (co < NCH) ? dnw[co * 256 + ci] : 0.f;
    unsigned short h, l; split_bf(w, h, l);
    wdh[i] = h; wdl[i] = l;
}

// ---------------- Stage 1: depthnet via MFMA, barrier-free, no LDS ---------
__global__ __launch_bounds__(256) void k_depthnet_direct(const float* __restrict__ x,
                                                         const unsigned short* __restrict__ wdh,
                                                         const unsigned short* __restrict__ wdl,
                                                         const float* __restrict__ dnb,
                                                         float* __restrict__ y)
{
    const int t  = threadIdx.x;
    const int w  = t >> 6;
    const int l  = t & 63;
    const int lp = l & 15;
    const int q  = l >> 4;
    const int n   = blockIdx.y;
    const int ct0 = blockIdx.z * 4;
    const int px  = blockIdx.x * 64 + w * 16 + lp;
    const bool pok = px < HW;
    const float* xl = x + (size_t)n * INC * HW + (pok ? px : 0);

    f32x4 acc[4];
#pragma unroll
    for (int ct = 0; ct < 4; ++ct) acc[ct] = (f32x4){0.f, 0.f, 0.f, 0.f};

#pragma unroll 2
    for (int ci0 = 0; ci0 < INC; ci0 += 32) {
        float bv[8];
#pragma unroll
        for (int jj = 0; jj < 8; ++jj)
            bv[jj] = xl[(size_t)(ci0 + q * 8 + jj) * HW];
        bf16x8 Bh, Bl;
#pragma unroll
        for (int jj = 0; jj < 8; ++jj) {
            unsigned short h, lo; split_bf(pok ? bv[jj] : 0.f, h, lo);
            Bh[jj] = (short)h; Bl[jj] = (short)lo;
        }
#pragma unroll
        for (int ct = 0; ct < 4; ++ct) {
            const size_t ab = (size_t)(((ct0 + ct) * 8 + (ci0 >> 5)) * 64 + l) * 8;
            bf16x8 Ah = *(const bf16x8*)&wdh[ab];
            bf16x8 Al = *(const bf16x8*)&wdl[ab];
            acc[ct] = __builtin_amdgcn_mfma_f32_16x16x32_bf16(Ah, Bh, acc[ct], 0, 0, 0);
            acc[ct] = __builtin_amdgcn_mfma_f32_16x16x32_bf16(Ah, Bl, acc[ct], 0, 0, 0);
            acc[ct] = __builtin_amdgcn_mfma_f32_16x16x32_bf16(Al, Bh, acc[ct], 0, 0, 0);
        }
    }
    if (pok) {
#pragma unroll
        for (int ct = 0; ct < 4; ++ct) {
#pragma unroll
            for (int j = 0; j < 4; ++j) {
                int co = (ct0 + ct) * 16 + q * 4 + j;
                if (co < NCH)
                    y[((size_t)n * NCH + co) * HW + px] = acc[ct][j] + dnb[co];
            }
        }
    }
}

// ---------------- Stage 2: softmax over 41 depth channels (in place) -------
__global__ __launch_bounds__(256) void k_softmax(float* __restrict__ y)
{
    int p = blockIdx.x * 256 + threadIdx.x;
    if (p >= NPIX) return;
    int n = p / HW, hw = p - n * HW;
    float* base = y + (size_t)n * NCH * HW + hw;
    float v[DDEP];
    float m = -3.4e38f;
#pragma unroll
    for (int d = 0; d < DDEP; ++d) { v[d] = base[(size_t)d * HW]; m = fmaxf(m, v[d]); }
    float s = 0.f;
#pragma unroll
    for (int d = 0; d < DDEP; ++d) { v[d] = expf(v[d] - m); s += v[d]; }
#pragma unroll
    for (int d = 0; d < DDEP; ++d) base[(size_t)d * HW] = v[d] / s;
}

// ---------------- Stage 3: geometry + lift + splat (atomics) ---------------
__global__ __launch_bounds__(256) void k_splat(const float* __restrict__ y,
                                               const float* __restrict__ rots,
                                               const float* __restrict__ trans,
                                               float* __restrict__ bev)
{
    int idx = blockIdx.x * 256 + threadIdx.x;
    if (idx >= NPIX * DDEP) return;
    int di = idx / NPIX;
    int p  = idx - di * NPIX;
    int n = p / HW, hw = p - n * HW;
    int wi = hw % WW, hi = hw / WW;
    const float su = 1599.0f / 99.0f;
    const float sv = 899.0f / 55.0f;
    float u = __fmul_rn((float)wi, su);
    float v = __fmul_rn((float)hi, sv);
    const float* r = rots + n * 9;
    const float* tr = trans + n * 3;
    float dd  = 4.0f + (float)di;
    float pxv = __fmul_rn(u, dd);
    float pyv = __fmul_rn(v, dd);
    float gx = __fadd_rn(__fadd_rn(__fadd_rn(__fmul_rn(r[0], pxv), __fmul_rn(r[1], pyv)), __fmul_rn(r[2], dd)), tr[0]);
    float gy = __fadd_rn(__fadd_rn(__fadd_rn(__fmul_rn(r[3], pxv), __fmul_rn(r[4], pyv)), __fmul_rn(r[5], dd)), tr[1]);
    float gz = __fadd_rn(__fadd_rn(__fadd_rn(__fmul_rn(r[6], pxv), __fmul_rn(r[7], pyv)), __fmul_rn(r[8], dd)), tr[2]);
    int cx = (int)__fdiv_rn(__fadd_rn(gx, 50.0f), 3.0f);
    int cy = (int)__fdiv_rn(__fadd_rn(gy, 50.0f), 3.0f);
    int cz = (int)__fdiv_rn(__fadd_rn(gz, 5.0f), 3.0f);
    if (cx >= 0 && cx < NXG && cy >= 0 && cy < NYG && cz >= 0 && cz < NZG) {
        const float* dbase = y + (size_t)n * NCH * HW + hw;
        const float* fbase = dbase + (size_t)DDEP * HW;
        float dval = dbase[(size_t)di * HW];
        float* vp = bev + (size_t)((cz * NYG + cy) * NXG + cx) * CFEAT;
#pragma unroll 8
        for (int c = 0; c < CFEAT; ++c) {
            atomicAdd(vp + c, __fmul_rn(dval, fbase[(size_t)c * HW]));
        }
    }
}

// ---------------- conv weight prep -> fragment layout ----------------------
__global__ __launch_bounds__(256) void k_wprep(const float* __restrict__ wgt,
                                               unsigned short* __restrict__ wh,
                                               unsigned short* __restrict__ wl,
                                               int COUT, int CIN)
{
    int i = blockIdx.x * 256 + threadIdx.x;
    int total = 9 * COUT * CIN;
    if (i >= total) return;
    int jj = i & 7, lane = (i >> 3) & 63;
    int r  = i >> 9;
    int nchk = CIN >> 5;
    int chk = r % nchk; r /= nchk;
    int ncog = COUT >> 4;
    int cog = r % ncog; int dydx = r / ncog;
    int co = cog * 16 + (lane & 15);
    int ci = chk * 32 + (lane >> 4) * 8 + jj;
    float w = wgt[((size_t)co * CIN + ci) * 9 + dydx];
    unsigned short h, l; split_bf(w, h, l);
    wh[i] = h; wl[i] = l;
}

// ---------------- bev [vox][c] -> act0 transposed [1225][128] bf16 h/l -----
__global__ __launch_bounds__(256) void k_bev2act(const float* __restrict__ bev,
                                                 unsigned short* __restrict__ ah,
                                                 unsigned short* __restrict__ al)
{
    int i = blockIdx.x * 256 + threadIdx.x;
    if (i >= NVOX * CFEAT) return;
    int vx = i >> 6, c = i & 63;
    int cz = vx / NPIXO, rem = vx - cz * NPIXO;
    int yy = rem / NXG, xx = rem - yy * NXG;
    int ch = c * 2 + cz;
    int pos = (yy + 1) * PADW + xx + 1;
    unsigned short h, l; split_bf(bev[i], h, l);
    ah[pos * 128 + ch] = h;
    al[pos * 128 + ch] = l;
}

// ---------------- MFMA 3x3 conv partials (split-bf16, 3-term) --------------
// 2-row y-tiles (17), XCD-grouped 1D grid: xcd = bid&7 owns all 17 y-tiles
// of G/8 (cob,sl) groups -> weight slice L2-resident on exactly one XCD.
template<int CIN, int COUT, int SL>
__global__ __launch_bounds__(256) void k_conv_mfma(const unsigned short* __restrict__ ah,
                                                   const unsigned short* __restrict__ al,
                                                   const unsigned short* __restrict__ wh,
                                                   const unsigned short* __restrict__ wl,
                                                   float* __restrict__ P)
{
    constexpr int CI_PER = CIN / SL;
    constexpr int NCOB = COUT / 64;
    constexpr int G    = NCOB * SL;      // (cob,sl) groups; G%8==0 or G*17%8==0
    constexpr int GX   = G / 8;
    constexpr int POSN = 140;            // 4 rows x 35 staged positions
    __shared__ unsigned short bs[POSN * 64];   // 17.9 KB
    const int t  = threadIdx.x;
    const int w  = t >> 6;
    const int l  = t & 63;
    const int lp = l & 15;
    const int q  = l >> 4;

    const int bid   = blockIdx.x;
    const int xcd   = bid & 7;
    const int slot  = bid >> 3;
    const int ytile = slot % 17;
    const int gon   = slot / 17;
    const int group = xcd * GX + gon;
    const int cobi  = group % NCOB;
    const int sl    = group / NCOB;

    const int y0  = ytile * 2;
    const int cob = cobi * 64 + w * 16;
    const int ci_base = sl * CI_PER;

    int  pos0[5];
    bool vld[5];
#pragma unroll
    for (int ct = 0; ct < 5; ++ct) {
        int tp = ct * 16 + lp;
        int r = tp / 33, c = tp - r * 33;
        bool v = (tp < 66) && (y0 + r < 33);
        vld[ct]  = v;
        pos0[ct] = v ? (r * 35 + c) : 0;
    }

    f32x4 acc[5];
#pragma unroll
    for (int ct = 0; ct < 5; ++ct) acc[ct] = (f32x4){0.f, 0.f, 0.f, 0.f};

    for (int chk = 0; chk < CI_PER; chk += 32) {
        const int ci0 = ci_base + chk;
        __syncthreads();
        for (int i = t; i < POSN * 8; i += 256) {
            int pos = i >> 3, s = i & 7;
            int gpos = y0 * 35 + pos;
            const unsigned short* src = (s < 4) ? ah : al;
            int sp = s ^ (pos & 7);
            uint4 val = make_uint4(0u, 0u, 0u, 0u);
            if (gpos < PADHW)
                val = *(const uint4*)&src[(size_t)gpos * CIN + ci0 + (s & 3) * 8];
            *(uint4*)&bs[pos * 64 + sp * 8] = val;
        }
        __syncthreads();

#pragma unroll 3
        for (int dydx = 0; dydx < 9; ++dydx) {
            int dy = dydx / 3, dx = dydx - dy * 3;
            int off = dy * 35 + dx;
            // fragment-contiguous A: one 1KB coalesced read per wave
            const size_t abase = (size_t)(((dydx * (COUT >> 4) + (cob >> 4)) * (CIN >> 5)
                                           + (ci0 >> 5)) * 64 + l) * 8;
            bf16x8 Ah = *(const bf16x8*)&wh[abase];
            bf16x8 Al = *(const bf16x8*)&wl[abase];
#pragma unroll
            for (int ct = 0; ct < 5; ++ct) {
                int pos = pos0[ct] + off;
                int sph = q ^ (pos & 7);
                bf16x8 Bh = *(const bf16x8*)&bs[pos * 64 + sph * 8];
                bf16x8 Bl = *(const bf16x8*)&bs[pos * 64 + (sph ^ 4) * 8];
                acc[ct] = __builtin_amdgcn_mfma_f32_16x16x32_bf16(Ah, Bh, acc[ct], 0, 0, 0);
                acc[ct] = __builtin_amdgcn_mfma_f32_16x16x32_bf16(Ah, Bl, acc[ct], 0, 0, 0);
                acc[ct] = __builtin_amdgcn_mfma_f32_16x16x32_bf16(Al, Bh, acc[ct], 0, 0, 0);
            }
        }
    }

#pragma unroll
    for (int ct = 0; ct < 5; ++ct) {
        if (!vld[ct]) continue;
        int gp = y0 * 33 + ct * 16 + lp;
        float* dst = P + ((size_t)sl * NPIXO + gp) * COUT + cob + q * 4;
        *(f32x4*)dst = acc[ct];
    }
}

// ---------------- reduce slices + BN + ReLU -> next act (or final out) -----
template<int SL>
__global__ __launch_bounds__(256) void k_finish(const float* __restrict__ P,
                                                const float* __restrict__ bns,
                                                const float* __restrict__ bnb,
                                                const float* __restrict__ bnm,
                                                const float* __restrict__ bnv,
                                                unsigned short* __restrict__ oh,
                                                unsigned short* __restrict__ ol,
                                                float* __restrict__ outf,
                                                int COUT)
{
    int i = blockIdx.x * 256 + threadIdx.x;
    if (i >= COUT * NPIXO) return;
    int co = i % COUT, p = i / COUT;
    float s = 0.f;
#pragma unroll
    for (int sl = 0; sl < SL; ++sl)
        s += P[((size_t)sl * NPIXO + p) * COUT + co];
    float sc = bns[co] / sqrtf(bnv[co] + 1e-5f);
    float bi = bnb[co] - bnm[co] * sc;
    float rv = fmaxf(fmaf(s, sc, bi), 0.f);
    if (outf) {
        outf[(size_t)co * NPIXO + p] = rv;
    } else {
        int yy = p / NXG, xx = p - yy * NXG;
        int pos = (yy + 1) * PADW + xx + 1;
        unsigned short h, lo; split_bf(rv, h, lo);
        oh[(size_t)pos * COUT + co] = h;
        ol[(size_t)pos * COUT + co] = lo;
    }
}

extern "C" void kernel_launch(void* const* d_in, const int* in_sizes, int n_in,
                              void* d_out, int out_size, void* d_ws, size_t ws_size,
                              hipStream_t stream)
{
    const float* x     = (const float*)d_in[0];
    const float* rots  = (const float*)d_in[1];
    const float* trans = (const float*)d_in[2];
    const float* dnw   = (const float*)d_in[3];
    const float* dnb   = (const float*)d_in[4];
    const float* bw1   = (const float*)d_in[5];
    const float* bn1s  = (const float*)d_in[6];
    const float* bn1b  = (const float*)d_in[7];
    const float* bn1m  = (const float*)d_in[8];
    const float* bn1v  = (const float*)d_in[9];
    const float* bw2   = (const float*)d_in[10];
    const float* bn2s  = (const float*)d_in[11];
    const float* bn2b  = (const float*)d_in[12];
    const float* bn2m  = (const float*)d_in[13];
    const float* bn2v  = (const float*)d_in[14];
    const float* bw3   = (const float*)d_in[15];
    const float* bn3s  = (const float*)d_in[16];
    const float* bn3b  = (const float*)d_in[17];
    const float* bn3m  = (const float*)d_in[18];
    const float* bn3v  = (const float*)d_in[19];
    const float* bw4   = (const float*)d_in[20];
    const float* bn4s  = (const float*)d_in[21];
    const float* bn4b  = (const float*)d_in[22];
    const float* bn4m  = (const float*)d_in[23];
    const float* bn4v  = (const float*)d_in[24];

    float* ws  = (float*)d_ws;
    float* y   = ws + Y_OFF;
    float* bev = ws + BEV_OFF;
    float* P   = ws + P_OFF;
    unsigned short* w1h = (unsigned short*)(ws + W1H_OFF);
    unsigned short* w1l = (unsigned short*)(ws + W1L_OFF);
    unsigned short* w2h = (unsigned short*)(ws + W2H_OFF);
    unsigned short* w2l = (unsigned short*)(ws + W2L_OFF);
    unsigned short* w3h = (unsigned short*)(ws + W3H_OFF);
    unsigned short* w3l = (unsigned short*)(ws + W3L_OFF);
    unsigned short* w4h = (unsigned short*)(ws + W4H_OFF);
    unsigned short* w4l = (unsigned short*)(ws + W4L_OFF);
    unsigned short* a0h = (unsigned short*)(ws + A0H_OFF);
    unsigned short* a0l = (unsigned short*)(ws + A0L_OFF);
    unsigned short* a1h = (unsigned short*)(ws + A1H_OFF);
    unsigned short* a1l = (unsigned short*)(ws + A1L_OFF);
    unsigned short* a2h = (unsigned short*)(ws + A2H_OFF);
    unsigned short* a2l = (unsigned short*)(ws + A2L_OFF);
    unsigned short* a3h = (unsigned short*)(ws + A3H_OFF);
    unsigned short* a3l = (unsigned short*)(ws + A3L_OFF);
    unsigned short* wdh = (unsigned short*)(ws + WDH_OFF);
    unsigned short* wdl = (unsigned short*)(ws + WDL_OFF);
    float* out = (float*)d_out;

    // zero bev accumulator + act buffers (their padded borders must be 0)
    hipMemsetAsync(bev, 0, (size_t)(P_OFF - BEV_OFF) * sizeof(float), stream);

    // depthnet: weight prep (lives in P region, dead until conv1) + MFMA GEMM
    k_wprep_dn<<<128, 256, 0, stream>>>(dnw, wdh, wdl);
    k_depthnet_direct<<<dim3(88, 6, 2), 256, 0, stream>>>(x, wdh, wdl, dnb, y);
    k_softmax<<<132, 256, 0, stream>>>(y);
    k_splat<<<(NPIX * DDEP + 255) / 256, 256, 0, stream>>>(y, rots, trans, bev);

    // conv weight prep (w3/w4 reuse the y region -> must be after splat)
    k_wprep<<<(9 * 128 * 128 + 255) / 256, 256, 0, stream>>>(bw1, w1h, w1l, 128, 128);
    k_wprep<<<(9 * 512 * 128 + 255) / 256, 256, 0, stream>>>(bw2, w2h, w2l, 512, 128);
    k_wprep<<<(9 * 512 * 512 + 255) / 256, 256, 0, stream>>>(bw3, w3h, w3l, 512, 512);
    k_wprep<<<(9 * 256 * 512 + 255) / 256, 256, 0, stream>>>(bw4, w4h, w4l, 256, 512);

    k_bev2act<<<(NVOX * CFEAT + 255) / 256, 256, 0, stream>>>(bev, a0h, a0l);

    // conv1: 128 -> 128   (136 blocks: 8 groups x 17 y-tiles)
    k_conv_mfma<128, 128, 4><<<136, 256, 0, stream>>>(a0h, a0l, w1h, w1l, P);
    k_finish<4><<<(128 * NPIXO + 255) / 256, 256, 0, stream>>>(P, bn1s, bn1b, bn1m, bn1v, a1h, a1l, nullptr, 128);
    // conv2: 128 -> 512   (544 blocks: 32 groups x 17 y-tiles)
    k_conv_mfma<128, 512, 4><<<544, 256, 0, stream>>>(a1h, a1l, w2h, w2l, P);
    k_finish<4><<<(512 * NPIXO + 255) / 256, 256, 0, stream>>>(P, bn2s, bn2b, bn2m, bn2v, a2h, a2l, nullptr, 512);
    // conv3: 512 -> 512, SL=8  (1088 blocks: 64 groups x 17 y-tiles)
    k_conv_mfma<512, 512, 8><<<1088, 256, 0, stream>>>(a2h, a2l, w3h, w3l, P);
    k_finish<8><<<(512 * NPIXO + 255) / 256, 256, 0, stream>>>(P, bn3s, bn3b, bn3m, bn3v, a3h, a3l, nullptr, 512);
    // conv4: 512 -> 256, SL=8  (544 blocks: 32 groups x 17 y-tiles)
    k_conv_mfma<512, 256, 8><<<544, 256, 0, stream>>>(a3h, a3l, w4h, w4l, P);
    k_finish<8><<<(256 * NPIXO + 255) / 256, 256, 0, stream>>>(P, bn4s, bn4b, bn4m, bn4v, nullptr, nullptr, out, 256);
}

// Round 8
// 134.941 us; speedup vs baseline: 10.6882x; 1.0720x over previous
//
#include <hip/hip_runtime.h>
#include <math.h>

#define NCAM  6
#define INC   256
#define HH    56
#define WW    100
#define HW    5600
#define NPIX  33600
#define DDEP  41
#define CFEAT 64
#define NCH   105          // 41 depth + 64 feat
#define NXG   33
#define NYG   33
#define NZG   2
#define NVOX  2178         // 2*33*33
#define PADW  35
#define PADHW 1225         // 35*35
#define NPIXO 1089         // 33*33

typedef short bf16x8 __attribute__((ext_vector_type(8)));
typedef float f32x4  __attribute__((ext_vector_type(4)));

// ---- workspace layout (floats); ws ~268 MB so no aliasing needed ----------
#define Y_OFF    0
#define Y_SZ     (NCAM * NCH * HW)          // 3,528,000
#define WDH_OFF  (Y_OFF + Y_SZ)             // dn weights: 128*256 shorts = 16384 fl
#define WDL_OFF  (WDH_OFF + 16384)
#define W1H_OFF  (WDL_OFF + 16384)          // 9*128*128 shorts = 73,728 fl
#define W1L_OFF  (W1H_OFF + 73728)
#define W2H_OFF  (W1L_OFF + 73728)          // 9*512*128 shorts = 294,912 fl
#define W2L_OFF  (W2H_OFF + 294912)
#define W3H_OFF  (W2L_OFF + 294912)         // 9*512*512 shorts = 1,179,648 fl
#define W3L_OFF  (W3H_OFF + 1179648)
#define W4H_OFF  (W3L_OFF + 1179648)        // 9*256*512 shorts = 589,824 fl
#define W4L_OFF  (W4H_OFF + 589824)
#define BEV_OFF  (W4L_OFF + 589824)
#define BEV_SZ   (NVOX * CFEAT)             // 139,392
#define A0H_OFF  (BEV_OFF + BEV_SZ)         // acts: [1225][CIN] bf16 (hi/lo)
#define A0L_OFF  (A0H_OFF + 78400)
#define A1H_OFF  (A0L_OFF + 78400)
#define A1L_OFF  (A1H_OFF + 78400)
#define A2H_OFF  (A1L_OFF + 78400)          // 1225*512 shorts = 313,600 fl
#define A2L_OFF  (A2H_OFF + 313600)
#define A3H_OFF  (A2L_OFF + 313600)
#define A3L_OFF  (A3H_OFF + 313600)
#define P_OFF    (A3L_OFF + 313600)
#define P_SZ     4460544                    // max slices*1089*COUT (8*1089*512)
#define WS_END   (P_OFF + P_SZ)             // ~56 MB

__device__ __forceinline__ unsigned short f2bf_rn(float f) {
    unsigned u = __builtin_bit_cast(unsigned, f);
    unsigned r = (u + 0x7FFFu + ((u >> 16) & 1u)) >> 16;
    return (unsigned short)r;
}
__device__ __forceinline__ void split_bf(float f, unsigned short& h, unsigned short& l) {
    h = f2bf_rn(f);
    float hf = __builtin_bit_cast(float, (unsigned)h << 16);
    l = f2bf_rn(f - hf);
}

// ---------------- unified weight prep (dn + 4 convs), fragment layout ------
__device__ __forceinline__ void wprep_conv(const float* __restrict__ wgt,
                                           unsigned short* __restrict__ wh,
                                           unsigned short* __restrict__ wl,
                                           int COUT, int CIN, int i)
{
    int jj = i & 7, lane = (i >> 3) & 63;
    int r  = i >> 9;
    int nchk = CIN >> 5;
    int chk = r % nchk; r /= nchk;
    int ncog = COUT >> 4;
    int cog = r % ncog; int dydx = r / ncog;
    int co = cog * 16 + (lane & 15);
    int ci = chk * 32 + (lane >> 4) * 8 + jj;
    float w = wgt[((size_t)co * CIN + ci) * 9 + dydx];
    unsigned short h, l; split_bf(w, h, l);
    wh[i] = h; wl[i] = l;
}

__global__ __launch_bounds__(256) void k_wprep_all(const float* __restrict__ dnw,
                                                   const float* __restrict__ bw1,
                                                   const float* __restrict__ bw2,
                                                   const float* __restrict__ bw3,
                                                   const float* __restrict__ bw4,
                                                   unsigned short* __restrict__ wdh,
                                                   unsigned short* __restrict__ wdl,
                                                   unsigned short* __restrict__ w1h,
                                                   unsigned short* __restrict__ w1l,
                                                   unsigned short* __restrict__ w2h,
                                                   unsigned short* __restrict__ w2l,
                                                   unsigned short* __restrict__ w3h,
                                                   unsigned short* __restrict__ w3l,
                                                   unsigned short* __restrict__ w4h,
                                                   unsigned short* __restrict__ w4l)
{
    int i = blockIdx.x * 256 + threadIdx.x;
    if (i < 32768) {   // depthnet [ct][chk][lane][jj]
        int jj = i & 7, lane = (i >> 3) & 63, chk = (i >> 9) & 7, ct = i >> 12;
        int co = ct * 16 + (lane & 15);
        int ci = chk * 32 + (lane >> 4) * 8 + jj;
        float w = (co < NCH) ? dnw[co * 256 + ci] : 0.f;
        unsigned short h, l; split_bf(w, h, l);
        wdh[i] = h; wdl[i] = l;
        return;
    }
    i -= 32768;
    if (i < 147456)  { wprep_conv(bw1, w1h, w1l, 128, 128, i); return; }
    i -= 147456;
    if (i < 589824)  { wprep_conv(bw2, w2h, w2l, 512, 128, i); return; }
    i -= 589824;
    if (i < 2359296) { wprep_conv(bw3, w3h, w3l, 512, 512, i); return; }
    i -= 2359296;
    if (i < 1179648) { wprep_conv(bw4, w4h, w4l, 256, 512, i); return; }
}

// ---------------- Stage 1+2: depthnet MFMA + fused softmax epilogue --------
// grid (88,6,2): z=0 owns co 0..63 (all 41 depth ch) -> in-register softmax
// via shfl_xor(16/32) across the 4 lanes sharing a px; z=1 owns co 64..104.
__global__ __launch_bounds__(256) void k_depthnet_fused(const float* __restrict__ x,
                                                        const unsigned short* __restrict__ wdh,
                                                        const unsigned short* __restrict__ wdl,
                                                        const float* __restrict__ dnb,
                                                        float* __restrict__ y)
{
    const int t  = threadIdx.x;
    const int w  = t >> 6;
    const int l  = t & 63;
    const int lp = l & 15;
    const int q  = l >> 4;
    const int n   = blockIdx.y;
    const int ct0 = blockIdx.z * 4;
    const int px  = blockIdx.x * 64 + w * 16 + lp;
    const bool pok = px < HW;
    const float* xl = x + (size_t)n * INC * HW + (pok ? px : 0);

    f32x4 acc[4];
#pragma unroll
    for (int ct = 0; ct < 4; ++ct) acc[ct] = (f32x4){0.f, 0.f, 0.f, 0.f};

#pragma unroll 2
    for (int ci0 = 0; ci0 < INC; ci0 += 32) {
        float bv[8];
#pragma unroll
        for (int jj = 0; jj < 8; ++jj)
            bv[jj] = xl[(size_t)(ci0 + q * 8 + jj) * HW];
        bf16x8 Bh, Bl;
#pragma unroll
        for (int jj = 0; jj < 8; ++jj) {
            unsigned short h, lo; split_bf(pok ? bv[jj] : 0.f, h, lo);
            Bh[jj] = (short)h; Bl[jj] = (short)lo;
        }
#pragma unroll
        for (int ct = 0; ct < 4; ++ct) {
            const size_t ab = (size_t)(((ct0 + ct) * 8 + (ci0 >> 5)) * 64 + l) * 8;
            bf16x8 Ah = *(const bf16x8*)&wdh[ab];
            bf16x8 Al = *(const bf16x8*)&wdl[ab];
            acc[ct] = __builtin_amdgcn_mfma_f32_16x16x32_bf16(Ah, Bh, acc[ct], 0, 0, 0);
            acc[ct] = __builtin_amdgcn_mfma_f32_16x16x32_bf16(Ah, Bl, acc[ct], 0, 0, 0);
            acc[ct] = __builtin_amdgcn_mfma_f32_16x16x32_bf16(Al, Bh, acc[ct], 0, 0, 0);
        }
    }

    // bias
    float v[4][4];
#pragma unroll
    for (int ct = 0; ct < 4; ++ct)
#pragma unroll
        for (int j = 0; j < 4; ++j) {
            int co = (ct0 + ct) * 16 + q * 4 + j;
            v[ct][j] = acc[ct][j] + ((co < NCH) ? dnb[co] : 0.f);
        }

    // fused softmax over depth channels (z=0 blocks hold co 0..63)
    if (ct0 == 0) {
        float m = -3.4e38f;
#pragma unroll
        for (int ct = 0; ct < 4; ++ct)
#pragma unroll
            for (int j = 0; j < 4; ++j) {
                int co = ct * 16 + q * 4 + j;
                if (co < DDEP) m = fmaxf(m, v[ct][j]);
            }
        m = fmaxf(m, __shfl_xor(m, 16));
        m = fmaxf(m, __shfl_xor(m, 32));
        float e[4][4];
        float s = 0.f;
#pragma unroll
        for (int ct = 0; ct < 4; ++ct)
#pragma unroll
            for (int j = 0; j < 4; ++j) {
                int co = ct * 16 + q * 4 + j;
                e[ct][j] = (co < DDEP) ? expf(v[ct][j] - m) : 0.f;
                s += e[ct][j];
            }
        s += __shfl_xor(s, 16);
        s += __shfl_xor(s, 32);
#pragma unroll
        for (int ct = 0; ct < 4; ++ct)
#pragma unroll
            for (int j = 0; j < 4; ++j) {
                int co = ct * 16 + q * 4 + j;
                if (co < DDEP) v[ct][j] = e[ct][j] / s;
            }
    }

    if (pok) {
#pragma unroll
        for (int ct = 0; ct < 4; ++ct)
#pragma unroll
            for (int j = 0; j < 4; ++j) {
                int co = (ct0 + ct) * 16 + q * 4 + j;
                if (co < NCH)
                    y[((size_t)n * NCH + co) * HW + px] = v[ct][j];
            }
    }
}

// ---------------- Stage 3: splat with LDS voxel cache + run-length dedup ---
// 32 px/block.  Phase 1: voxel index per (px,d) once (exact rn sequence).
// Phase 2: 8 threads/px (8 ch each, feat in regs), flush atomics only when
// the voxel changes along the ray (~3 consecutive depths share a voxel).
__global__ __launch_bounds__(256) void k_splat2(const float* __restrict__ y,
                                                const float* __restrict__ rots,
                                                const float* __restrict__ trans,
                                                float* __restrict__ bev)
{
    __shared__ int vox[32 * DDEP];
    const int t  = threadIdx.x;
    const int p0 = blockIdx.x * 32;

    for (int k = t; k < 32 * DDEP; k += 256) {
        int pl = k / DDEP, d = k - pl * DDEP;
        int p = p0 + pl;
        int vx = -1;
        {
            int n = p / HW, hw = p - n * HW;
            int wi = hw % WW, hi = hw / WW;
            const float su = 1599.0f / 99.0f;
            const float sv = 899.0f / 55.0f;
            float u = __fmul_rn((float)wi, su);
            float v = __fmul_rn((float)hi, sv);
            const float* r = rots + n * 9;
            const float* tr = trans + n * 3;
            float dd  = 4.0f + (float)d;
            float pxv = __fmul_rn(u, dd);
            float pyv = __fmul_rn(v, dd);
            float gx = __fadd_rn(__fadd_rn(__fadd_rn(__fmul_rn(r[0], pxv), __fmul_rn(r[1], pyv)), __fmul_rn(r[2], dd)), tr[0]);
            float gy = __fadd_rn(__fadd_rn(__fadd_rn(__fmul_rn(r[3], pxv), __fmul_rn(r[4], pyv)), __fmul_rn(r[5], dd)), tr[1]);
            float gz = __fadd_rn(__fadd_rn(__fadd_rn(__fmul_rn(r[6], pxv), __fmul_rn(r[7], pyv)), __fmul_rn(r[8], dd)), tr[2]);
            int cx = (int)__fdiv_rn(__fadd_rn(gx, 50.0f), 3.0f);
            int cy = (int)__fdiv_rn(__fadd_rn(gy, 50.0f), 3.0f);
            int cz = (int)__fdiv_rn(__fadd_rn(gz, 5.0f), 3.0f);
            if (cx >= 0 && cx < NXG && cy >= 0 && cy < NYG && cz >= 0 && cz < NZG)
                vx = (cz * NYG + cy) * NXG + cx;
        }
        vox[k] = vx;
    }
    __syncthreads();

    const int g  = t >> 5;    // channel group 0..7
    const int pl = t & 31;
    const int p  = p0 + pl;
    int n = p / HW, hw = p - n * HW;
    const float* dbase = y + (size_t)n * NCH * HW + hw;
    const float* fbase = dbase + (size_t)DDEP * HW;
    float f[8];
#pragma unroll
    for (int j = 0; j < 8; ++j) f[j] = fbase[(size_t)(g * 8 + j) * HW];

    float a[8];
#pragma unroll
    for (int j = 0; j < 8; ++j) a[j] = 0.f;
    int cur = -1;
    for (int d = 0; d < DDEP; ++d) {
        int vx = vox[pl * DDEP + d];
        if (vx != cur) {
            if (cur >= 0) {
                float* vp = bev + (size_t)cur * CFEAT + g * 8;
#pragma unroll
                for (int j = 0; j < 8; ++j) atomicAdd(vp + j, a[j]);
            }
            cur = vx;
#pragma unroll
            for (int j = 0; j < 8; ++j) a[j] = 0.f;
        }
        if (vx >= 0) {
            float dval = dbase[(size_t)d * HW];
#pragma unroll
            for (int j = 0; j < 8; ++j) a[j] += __fmul_rn(dval, f[j]);
        }
    }
    if (cur >= 0) {
        float* vp = bev + (size_t)cur * CFEAT + g * 8;
#pragma unroll
        for (int j = 0; j < 8; ++j) atomicAdd(vp + j, a[j]);
    }
}

// ---------------- bev [vox][c] -> act0 transposed [1225][128] bf16 h/l -----
__global__ __launch_bounds__(256) void k_bev2act(const float* __restrict__ bev,
                                                 unsigned short* __restrict__ ah,
                                                 unsigned short* __restrict__ al)
{
    int i = blockIdx.x * 256 + threadIdx.x;
    if (i >= NVOX * CFEAT) return;
    int vx = i >> 6, c = i & 63;
    int cz = vx / NPIXO, rem = vx - cz * NPIXO;
    int yy = rem / NXG, xx = rem - yy * NXG;
    int ch = c * 2 + cz;
    int pos = (yy + 1) * PADW + xx + 1;
    unsigned short h, l; split_bf(bev[i], h, l);
    ah[pos * 128 + ch] = h;
    al[pos * 128 + ch] = l;
}

// ---------------- MFMA 3x3 conv partials (split-bf16, 3-term) --------------
template<int CIN, int COUT, int SL>
__global__ __launch_bounds__(256) void k_conv_mfma(const unsigned short* __restrict__ ah,
                                                   const unsigned short* __restrict__ al,
                                                   const unsigned short* __restrict__ wh,
                                                   const unsigned short* __restrict__ wl,
                                                   float* __restrict__ P)
{
    constexpr int CI_PER = CIN / SL;
    constexpr int NCOB = COUT / 64;
    constexpr int G    = NCOB * SL;
    constexpr int GX   = G / 8;
    constexpr int POSN = 140;
    __shared__ unsigned short bs[POSN * 64];
    const int t  = threadIdx.x;
    const int w  = t >> 6;
    const int l  = t & 63;
    const int lp = l & 15;
    const int q  = l >> 4;

    const int bid   = blockIdx.x;
    const int xcd   = bid & 7;
    const int slot  = bid >> 3;
    const int ytile = slot % 17;
    const int gon   = slot / 17;
    const int group = xcd * GX + gon;
    const int cobi  = group % NCOB;
    const int sl    = group / NCOB;

    const int y0  = ytile * 2;
    const int cob = cobi * 64 + w * 16;
    const int ci_base = sl * CI_PER;

    int  pos0[5];
    bool vld[5];
#pragma unroll
    for (int ct = 0; ct < 5; ++ct) {
        int tp = ct * 16 + lp;
        int r = tp / 33, c = tp - r * 33;
        bool v = (tp < 66) && (y0 + r < 33);
        vld[ct]  = v;
        pos0[ct] = v ? (r * 35 + c) : 0;
    }

    f32x4 acc[5];
#pragma unroll
    for (int ct = 0; ct < 5; ++ct) acc[ct] = (f32x4){0.f, 0.f, 0.f, 0.f};

    for (int chk = 0; chk < CI_PER; chk += 32) {
        const int ci0 = ci_base + chk;
        __syncthreads();
        for (int i = t; i < POSN * 8; i += 256) {
            int pos = i >> 3, s = i & 7;
            int gpos = y0 * 35 + pos;
            const unsigned short* src = (s < 4) ? ah : al;
            int sp = s ^ (pos & 7);
            uint4 val = make_uint4(0u, 0u, 0u, 0u);
            if (gpos < PADHW)
                val = *(const uint4*)&src[(size_t)gpos * CIN + ci0 + (s & 3) * 8];
            *(uint4*)&bs[pos * 64 + sp * 8] = val;
        }
        __syncthreads();

#pragma unroll 3
        for (int dydx = 0; dydx < 9; ++dydx) {
            int dy = dydx / 3, dx = dydx - dy * 3;
            int off = dy * 35 + dx;
            const size_t abase = (size_t)(((dydx * (COUT >> 4) + (cob >> 4)) * (CIN >> 5)
                                           + (ci0 >> 5)) * 64 + l) * 8;
            bf16x8 Ah = *(const bf16x8*)&wh[abase];
            bf16x8 Al = *(const bf16x8*)&wl[abase];
#pragma unroll
            for (int ct = 0; ct < 5; ++ct) {
                int pos = pos0[ct] + off;
                int sph = q ^ (pos & 7);
                bf16x8 Bh = *(const bf16x8*)&bs[pos * 64 + sph * 8];
                bf16x8 Bl = *(const bf16x8*)&bs[pos * 64 + (sph ^ 4) * 8];
                acc[ct] = __builtin_amdgcn_mfma_f32_16x16x32_bf16(Ah, Bh, acc[ct], 0, 0, 0);
                acc[ct] = __builtin_amdgcn_mfma_f32_16x16x32_bf16(Ah, Bl, acc[ct], 0, 0, 0);
                acc[ct] = __builtin_amdgcn_mfma_f32_16x16x32_bf16(Al, Bh, acc[ct], 0, 0, 0);
            }
        }
    }

#pragma unroll
    for (int ct = 0; ct < 5; ++ct) {
        if (!vld[ct]) continue;
        int gp = y0 * 33 + ct * 16 + lp;
        float* dst = P + ((size_t)sl * NPIXO + gp) * COUT + cob + q * 4;
        *(f32x4*)dst = acc[ct];
    }
}

// ---------------- reduce slices + BN + ReLU -> next act (or final out) -----
template<int SL>
__global__ __launch_bounds__(256) void k_finish(const float* __restrict__ P,
                                                const float* __restrict__ bns,
                                                const float* __restrict__ bnb,
                                                const float* __restrict__ bnm,
                                                const float* __restrict__ bnv,
                                                unsigned short* __restrict__ oh,
                                                unsigned short* __restrict__ ol,
                                                float* __restrict__ outf,
                                                int COUT)
{
    int i = blockIdx.x * 256 + threadIdx.x;
    if (i >= COUT * NPIXO) return;
    int co = i % COUT, p = i / COUT;
    float s = 0.f;
#pragma unroll
    for (int sl = 0; sl < SL; ++sl)
        s += P[((size_t)sl * NPIXO + p) * COUT + co];
    float sc = bns[co] / sqrtf(bnv[co] + 1e-5f);
    float bi = bnb[co] - bnm[co] * sc;
    float rv = fmaxf(fmaf(s, sc, bi), 0.f);
    if (outf) {
        outf[(size_t)co * NPIXO + p] = rv;
    } else {
        int yy = p / NXG, xx = p - yy * NXG;
        int pos = (yy + 1) * PADW + xx + 1;
        unsigned short h, lo; split_bf(rv, h, lo);
        oh[(size_t)pos * COUT + co] = h;
        ol[(size_t)pos * COUT + co] = lo;
    }
}

extern "C" void kernel_launch(void* const* d_in, const int* in_sizes, int n_in,
                              void* d_out, int out_size, void* d_ws, size_t ws_size,
                              hipStream_t stream)
{
    const float* x     = (const float*)d_in[0];
    const float* rots  = (const float*)d_in[1];
    const float* trans = (const float*)d_in[2];
    const float* dnw   = (const float*)d_in[3];
    const float* dnb   = (const float*)d_in[4];
    const float* bw1   = (const float*)d_in[5];
    const float* bn1s  = (const float*)d_in[6];
    const float* bn1b  = (const float*)d_in[7];
    const float* bn1m  = (const float*)d_in[8];
    const float* bn1v  = (const float*)d_in[9];
    const float* bw2   = (const float*)d_in[10];
    const float* bn2s  = (const float*)d_in[11];
    const float* bn2b  = (const float*)d_in[12];
    const float* bn2m  = (const float*)d_in[13];
    const float* bn2v  = (const float*)d_in[14];
    const float* bw3   = (const float*)d_in[15];
    const float* bn3s  = (const float*)d_in[16];
    const float* bn3b  = (const float*)d_in[17];
    const float* bn3m  = (const float*)d_in[18];
    const float* bn3v  = (const float*)d_in[19];
    const float* bw4   = (const float*)d_in[20];
    const float* bn4s  = (const float*)d_in[21];
    const float* bn4b  = (const float*)d_in[22];
    const float* bn4m  = (const float*)d_in[23];
    const float* bn4v  = (const float*)d_in[24];

    float* ws  = (float*)d_ws;
    float* y   = ws + Y_OFF;
    float* bev = ws + BEV_OFF;
    float* P   = ws + P_OFF;
    unsigned short* wdh = (unsigned short*)(ws + WDH_OFF);
    unsigned short* wdl = (unsigned short*)(ws + WDL_OFF);
    unsigned short* w1h = (unsigned short*)(ws + W1H_OFF);
    unsigned short* w1l = (unsigned short*)(ws + W1L_OFF);
    unsigned short* w2h = (unsigned short*)(ws + W2H_OFF);
    unsigned short* w2l = (unsigned short*)(ws + W2L_OFF);
    unsigned short* w3h = (unsigned short*)(ws + W3H_OFF);
    unsigned short* w3l = (unsigned short*)(ws + W3L_OFF);
    unsigned short* w4h = (unsigned short*)(ws + W4H_OFF);
    unsigned short* w4l = (unsigned short*)(ws + W4L_OFF);
    unsigned short* a0h = (unsigned short*)(ws + A0H_OFF);
    unsigned short* a0l = (unsigned short*)(ws + A0L_OFF);
    unsigned short* a1h = (unsigned short*)(ws + A1H_OFF);
    unsigned short* a1l = (unsigned short*)(ws + A1L_OFF);
    unsigned short* a2h = (unsigned short*)(ws + A2H_OFF);
    unsigned short* a2l = (unsigned short*)(ws + A2L_OFF);
    unsigned short* a3h = (unsigned short*)(ws + A3H_OFF);
    unsigned short* a3l = (unsigned short*)(ws + A3L_OFF);
    float* out = (float*)d_out;

    // zero bev accumulator + act buffers (their padded borders must be 0)
    hipMemsetAsync(bev, 0, (size_t)(P_OFF - BEV_OFF) * sizeof(float), stream);

    // all weight preps in one kernel (own regions, no aliasing)
    k_wprep_all<<<16832, 256, 0, stream>>>(dnw, bw1, bw2, bw3, bw4,
                                           wdh, wdl, w1h, w1l, w2h, w2l,
                                           w3h, w3l, w4h, w4l);
    // depthnet + fused softmax
    k_depthnet_fused<<<dim3(88, 6, 2), 256, 0, stream>>>(x, wdh, wdl, dnb, y);
    // splat with voxel dedup (33600/32 = 1050 blocks)
    k_splat2<<<1050, 256, 0, stream>>>(y, rots, trans, bev);

    k_bev2act<<<(NVOX * CFEAT + 255) / 256, 256, 0, stream>>>(bev, a0h, a0l);

    // conv1: 128 -> 128   (136 blocks)
    k_conv_mfma<128, 128, 4><<<136, 256, 0, stream>>>(a0h, a0l, w1h, w1l, P);
    k_finish<4><<<(128 * NPIXO + 255) / 256, 256, 0, stream>>>(P, bn1s, bn1b, bn1m, bn1v, a1h, a1l, nullptr, 128);
    // conv2: 128 -> 512   (544 blocks)
    k_conv_mfma<128, 512, 4><<<544, 256, 0, stream>>>(a1h, a1l, w2h, w2l, P);
    k_finish<4><<<(512 * NPIXO + 255) / 256, 256, 0, stream>>>(P, bn2s, bn2b, bn2m, bn2v, a2h, a2l, nullptr, 512);
    // conv3: 512 -> 512, SL=8  (1088 blocks)
    k_conv_mfma<512, 512, 8><<<1088, 256, 0, stream>>>(a2h, a2l, w3h, w3l, P);
    k_finish<8><<<(512 * NPIXO + 255) / 256, 256, 0, stream>>>(P, bn3s, bn3b, bn3m, bn3v, a3h, a3l, nullptr, 512);
    // conv4: 512 -> 256, SL=8  (544 blocks, final fp32 out [256][33][33])
    k_conv_mfma<512, 256, 8><<<544, 256, 0, stream>>>(a3h, a3l, w4h, w4l, P);
    k_finish<8><<<(256 * NPIXO + 255) / 256, 256, 0, stream>>>(P, bn4s, bn4b, bn4m, bn4v, nullptr, nullptr, out, 256);
}